// Round 10
// baseline (7528.685 us; speedup 1.0000x reference)
//
#include <hip/hip_runtime.h>
#include <math.h>

#define TB 256      // batch
#define TT 512      // timesteps
#define TIN 128     // input size
#define TH 1024     // hidden
#define TOUT 9      // output coords
#define KD 1152     // TIN + TH

typedef _Float16 half8 __attribute__((ext_vector_type(8)));
typedef float f32x4 __attribute__((ext_vector_type(4)));

// ---- workspace layout (BYTE offsets) ----
#define OB_WHF   0ull
#define SB_WHF   (128ull*2*36*64*8*2)   // 9,437,184 B  f16 B-fragments [wcg][nt][kc][l][j]
#define OB_WCB   (OB_WHF + SB_WHF)      // Wcombo fp32 [9][1024]
#define SB_WCB   (9ull*1024*4)
#define OB_BCB   (OB_WCB + SB_WCB)      // bcombo fp32 [9] (pad 16)
#define SB_BCB   64ull
#define OB_B0    (OB_BCB + SB_BCB)      // bias t==0 [4096] fp32
#define SB_B0    (4096ull*4)
#define OB_BC    (OB_B0 + SB_B0)        // bias t>0  [4096] fp32
#define SB_BC    (4096ull*4)
#define OB_H0    (OB_BC + SB_BC)        // h_cell ping [256][1024] f16
#define SB_H     (256ull*1024*2)
#define OB_H1    (OB_H0 + SB_H)         // h_cell pong
#define OB_GC    (OB_H1 + SB_H)         // barrier counters (two halves, 128B lines)
#define OB_END   (OB_GC + 8192ull)      // ~10.5 MB total

// fragment address for gate col `col` (0..4095), k (0..1151):
//   q=col>>10 (gate), hcol=col&1023, wcg=hcol>>3, jj=hcol&7, c=(q<<3)|jj,
//   nt=c>>4, n=c&15, kc=k>>5, ls=(k>>3)&3, je=k&7, lane=(ls<<4)|n
__device__ __forceinline__ size_t frag_addr(int col, int k) {
  int q = col >> 10, hcol = col & 1023;
  int wcg = hcol >> 3, jj = hcol & 7;
  int c = (q << 3) | jj;
  int nt = c >> 4, n = c & 15;
  int kc = k >> 5, ls = (k >> 3) & 3, je = k & 7;
  return ((((size_t)wcg * 2 + nt) * 36 + kc) * 64 + ((ls << 4) | n)) * 8 + je;
}

// ---- agent-scope (LLC write-through) 16B h store as 2x8B relaxed atomics ----
__device__ __forceinline__ void st_h16_agent(_Float16* p, uint4 v) {
  union { uint4 q; unsigned long long u[2]; } c; c.q = v;
  __hip_atomic_store((unsigned long long*)p,     c.u[0], __ATOMIC_RELAXED, __HIP_MEMORY_SCOPE_AGENT);
  __hip_atomic_store((unsigned long long*)p + 1, c.u[1], __ATOMIC_RELAXED, __HIP_MEMORY_SCOPE_AGENT);
}

// ---------------- prep kernels (unchanged, verified rounds 5-9) ----------------

__global__ __launch_bounds__(256) void k_combo(const float* __restrict__ W_h2o,
                                               const float* __restrict__ W_h2h,
                                               const float* __restrict__ b_h2h,
                                               const float* __restrict__ b_h2o,
                                               float* __restrict__ Wcombo,
                                               float* __restrict__ bcombo) {
  int gid = blockIdx.x * 256 + threadIdx.x;
  if (gid < 9 * 1024) {
    int r = gid >> 10, m = gid & 1023;
    float s = 0.f;
    for (int j = 0; j < 1024; ++j) s += W_h2o[r * 1024 + j] * W_h2h[j * 1024 + m];
    Wcombo[gid] = s;
  }
  if (gid < 9) {
    float s = b_h2o[gid];
    for (int j = 0; j < 1024; ++j) s += W_h2o[gid * 1024 + j] * b_h2h[j];
    bcombo[gid] = s;
  }
}

__global__ __launch_bounds__(256) void k_wblk(const float* __restrict__ W_hh,
                                              const float* __restrict__ W_ih,
                                              const float* __restrict__ W_h2o,
                                              const float* __restrict__ W_h2h,
                                              _Float16* __restrict__ Whf) {
  __shared__ float As2[16][68];
  __shared__ float Bs[16][68];
  __shared__ float Wio_s[64][12];
  __shared__ float Bo[9][16];
  const int tid = threadIdx.x;
  const int bm = (blockIdx.x & 15) * 64;   // m tile
  const int bc = (blockIdx.x >> 4) * 64;   // col tile
  const int tx = tid & 15, ty = tid >> 4;
  const int cl = tid >> 2, kq4 = tid & 3;

  for (int i = tid; i < 64 * 9; i += 256) {
    int row = i / 9, r = i % 9;
    Wio_s[row][r] = W_ih[(size_t)(bc + row) * 137 + 128 + r];
  }

  float acc[4][4];
#pragma unroll
  for (int i = 0; i < 4; ++i)
#pragma unroll
    for (int j = 0; j < 4; ++j) acc[i][j] = 0.f;

  for (int k0 = 0; k0 < 1024; k0 += 16) {
    __syncthreads();
    if (tid < 144) { int r = tid >> 4, kk = tid & 15; Bo[r][kk] = W_h2o[(size_t)r * 1024 + k0 + kk]; }
    { int kk = tid >> 4, q = tid & 15;
      float4 v = *(const float4*)(W_h2h + (size_t)(k0 + kk) * 1024 + bm + q * 4);
      *(float4*)&Bs[kk][q * 4] = v; }
    float4 av = *(const float4*)(W_hh + (size_t)(bc + cl) * 1024 + k0 + kq4 * 4);
    __syncthreads();
    {
      float c0 = 0.f, c1 = 0.f, c2 = 0.f, c3 = 0.f;
#pragma unroll
      for (int r = 0; r < 9; ++r) {
        float wio = Wio_s[cl][r];
        c0 += wio * Bo[r][kq4 * 4 + 0];
        c1 += wio * Bo[r][kq4 * 4 + 1];
        c2 += wio * Bo[r][kq4 * 4 + 2];
        c3 += wio * Bo[r][kq4 * 4 + 3];
      }
      As2[kq4 * 4 + 0][cl] = av.x + c0;
      As2[kq4 * 4 + 1][cl] = av.y + c1;
      As2[kq4 * 4 + 2][cl] = av.z + c2;
      As2[kq4 * 4 + 3][cl] = av.w + c3;
    }
    __syncthreads();
#pragma unroll
    for (int kk = 0; kk < 16; ++kk) {
      float4 a = *(const float4*)&As2[kk][ty * 4];
      float4 bv = *(const float4*)&Bs[kk][tx * 4];
      acc[0][0] += a.x * bv.x; acc[0][1] += a.x * bv.y; acc[0][2] += a.x * bv.z; acc[0][3] += a.x * bv.w;
      acc[1][0] += a.y * bv.x; acc[1][1] += a.y * bv.y; acc[1][2] += a.y * bv.z; acc[1][3] += a.y * bv.w;
      acc[2][0] += a.z * bv.x; acc[2][1] += a.z * bv.y; acc[2][2] += a.z * bv.z; acc[2][3] += a.z * bv.w;
      acc[3][0] += a.w * bv.x; acc[3][1] += a.w * bv.y; acc[3][2] += a.w * bv.z; acc[3][3] += a.w * bv.w;
    }
  }
#pragma unroll
  for (int i = 0; i < 4; ++i)
#pragma unroll
    for (int j = 0; j < 4; ++j) {
      int col = bc + ty * 4 + i;          // gate col
      int m = bm + tx * 4 + j;            // h index -> k = 128+m
      Whf[frag_addr(col, 128 + m)] = (_Float16)acc[i][j];
    }
}

__global__ __launch_bounds__(256) void k_bias(const float* __restrict__ b_ih,
                                              const float* __restrict__ b_hh,
                                              const float* __restrict__ W_hh,
                                              const float* __restrict__ W_ih,
                                              const float* __restrict__ b_h2h,
                                              const float* __restrict__ bcombo,
                                              float* __restrict__ b0,
                                              float* __restrict__ bconst) {
  int col = blockIdx.x * 256 + threadIdx.x;
  float base = b_ih[col] + b_hh[col];
  b0[col] = base;
  float s = 0.f;
  for (int j = 0; j < 1024; ++j) s += W_hh[(size_t)col * 1024 + j] * b_h2h[j];
#pragma unroll
  for (int r = 0; r < 9; ++r) s += W_ih[(size_t)col * 137 + 128 + r] * bcombo[r];
  bconst[col] = base + s;
}

__global__ __launch_bounds__(256) void k_fillx(const float* __restrict__ W_ih,
                                               _Float16* __restrict__ Whf) {
  int gid = blockIdx.x * 256 + threadIdx.x;   // 4096*128
  int col = gid >> 7, k = gid & 127;
  Whf[frag_addr(col, k)] = (_Float16)W_ih[(size_t)col * 137 + k];
}

__global__ void k_len(const int* __restrict__ len, float* __restrict__ dout) {
  int i = threadIdx.x;
  if (i < TB) dout[(size_t)TB * TT * TOUT + i] = (float)len[i];
}

// ---------------- persistent main kernel ----------------
// Same structure as round 9 (split per-half tree barriers, write-through h
// stores, cached h reads + invalidate-only acquire, uniform out-GEMV).
// NEW: sched_barrier(0) pins ALL 18 A-fragment loads above the MFMA loop —
// the compiler may no longer sink them (r9's VGPR=52 proved it did), so the
// 18 LLC-latency exposures collapse to one pipelined drain.

__device__ __forceinline__ float sigm(float v) { return 1.f / (1.f + __expf(-v)); }
__device__ __forceinline__ float tanh_f(float v) {
  float e2 = __expf(2.f * v);
  return (e2 - 1.f) / (e2 + 1.f);
}

__global__ __launch_bounds__(1024, 1) void k_main(const float* __restrict__ x,
                                                  const _Float16* __restrict__ Whf,
                                                  const float* __restrict__ Wc,
                                                  const float* __restrict__ b0,
                                                  const float* __restrict__ bcf,
                                                  const float* __restrict__ bcombo,
                                                  _Float16* __restrict__ hA,
                                                  _Float16* __restrict__ hB,
                                                  unsigned* __restrict__ gs,
                                                  float* __restrict__ dout) {
  __shared__ _Float16 Wl[2 * 36 * 64 * 8];   // 73,728 B
  __shared__ float gbuf[2][128][36];         // 36,864 B (K-half partials)
  __shared__ _Float16 htmp[128][8];          //  2,048 B
  __shared__ float bias_s[2][32];
  __shared__ float bco_s[12];
  __shared__ int sAbort;

  const int bx = blockIdx.x;
  const int half_id = bx >> 7;       // 0/1: independent batch-half
  const int wcg = bx & 127;          // col-group: h-cols 8*wcg..+7
  const int B0 = half_id * 128;      // batch base
  const int myb = B0 + wcg;          // this block's out-GEMV batch
  const int grp = wcg >> 4;          // barrier group within half (8 groups x 16)
  const int tid = threadIdx.x;
  const int lane = tid & 63;
  const int wv = tid >> 6;
  const int mt = wv & 7, kh = wv >> 3;

  unsigned* hbase = gs + half_id * 1024;     // per-half barrier region
  unsigned* gcnt_grp = hbase + grp * 32;     // arrival counter (own 128B line)
  unsigned* gcnt_root = hbase + 8 * 32;      // root counter (8 leads)
  unsigned* grel = hbase + (9 + grp) * 32;   // group release word
  unsigned* gabort = gs + 1984;              // global abort flag (shared)

  {  // stage W fragments once (reused 512 steps)
    const uint4* src = (const uint4*)(Whf + (size_t)wcg * (2 * 36 * 64 * 8));
    uint4* dst = (uint4*)Wl;
    for (int i = tid; i < 2 * 36 * 64 * 8 / 8; i += 1024) dst[i] = src[i];
  }
  if (tid == 0) sAbort = 0;
  if (tid < 9) bco_s[tid] = bcombo[tid];
  if (tid < 32) {
    int g = (tid >> 3) * 1024 + wcg * 8 + (tid & 7);   // c=(q<<3)|jj -> gate col
    bias_s[0][tid] = b0[g];
    bias_s[1][tid] = bcf[g];
  }
  float cs = 0.f;   // cell state of (batch B0+(tid>>3), h-col 8*wcg+(tid&7))
  __syncthreads();

  const _Float16* ha = hA;   // h_cell(t-1), zeroed by memset
  _Float16* hn = hB;

  const int bA = B0 + mt * 16 + (lane & 15);   // A-fragment batch row
  const int ko = (lane >> 4) * 8;              // A-fragment k offset within 32-chunk
  const _Float16* wl0 = Wl + (size_t)lane * 8;
  const _Float16* wlb = wl0 + (size_t)(kh * 18) * 512;
  unsigned myLead = 0;

  for (int t = 0; t < TT; ++t) {
    // ---- A-fragment loads: ALL issued and pinned above the MFMA loop ----
    f32x4 acc0 = {0.f, 0.f, 0.f, 0.f};
    f32x4 acc1 = {0.f, 0.f, 0.f, 0.f};
    const _Float16* hrow = ha + (size_t)bA * TH;
    half8 af[18];
    if (kh == 0) {
      const float* xrow = x + ((size_t)bA * TT + t) * TIN;
      float4 xv[8];
#pragma unroll
      for (int i = 0; i < 4; ++i) {
        xv[2 * i]     = *(const float4*)(xrow + i * 32 + ko);
        xv[2 * i + 1] = *(const float4*)(xrow + i * 32 + ko + 4);
      }
#pragma unroll
      for (int lc = 4; lc < 18; ++lc)
        af[lc] = *(const half8*)(hrow + (lc * 32 - 128 + ko));
#pragma unroll
      for (int i = 0; i < 4; ++i) {
        half8 a;
        a[0] = (_Float16)xv[2 * i].x; a[1] = (_Float16)xv[2 * i].y;
        a[2] = (_Float16)xv[2 * i].z; a[3] = (_Float16)xv[2 * i].w;
        a[4] = (_Float16)xv[2 * i + 1].x; a[5] = (_Float16)xv[2 * i + 1].y;
        a[6] = (_Float16)xv[2 * i + 1].z; a[7] = (_Float16)xv[2 * i + 1].w;
        af[i] = a;
      }
    } else {
#pragma unroll
      for (int lc = 0; lc < 18; ++lc)
        af[lc] = *(const half8*)(hrow + ((18 + lc) * 32 - 128 + ko));
    }
    // No instruction may cross: loads stay issued above, MFMAs below.
    __builtin_amdgcn_sched_barrier(0);

    // ---- MFMA loop: B from LDS, A from in-flight registers ----
#pragma unroll
    for (int lc = 0; lc < 18; ++lc) {
      half8 bf0 = *(const half8*)(wlb + (size_t)lc * 512);
      half8 bf1 = *(const half8*)(wlb + (size_t)(36 + lc) * 512);
      acc0 = __builtin_amdgcn_mfma_f32_16x16x32_f16(af[lc], bf0, acc0, 0, 0, 0);
      acc1 = __builtin_amdgcn_mfma_f32_16x16x32_f16(af[lc], bf1, acc1, 0, 0, 0);
    }
    {  // D layout: col = lane&15, row = (lane>>4)*4 + r
      int rb = mt * 16 + (lane >> 4) * 4;
      int cc = lane & 15;
#pragma unroll
      for (int r = 0; r < 4; ++r) {
        gbuf[kh][rb + r][cc] = acc0[r];
        gbuf[kh][rb + r][16 + cc] = acc1[r];
      }
    }
    __syncthreads();

    // ---- LSTM finish: thread owns (fb=tid>>3, fj=tid&7); cs in registers ----
    {
      const int fb = tid >> 3, fj = tid & 7;
      const float* bs = bias_s[(t > 0) ? 1 : 0];
      float vi = gbuf[0][fb][fj]      + gbuf[1][fb][fj]      + bs[fj];
      float vf = gbuf[0][fb][8 + fj]  + gbuf[1][fb][8 + fj]  + bs[8 + fj];
      float vg = gbuf[0][fb][16 + fj] + gbuf[1][fb][16 + fj] + bs[16 + fj];
      float vo = gbuf[0][fb][24 + fj] + gbuf[1][fb][24 + fj] + bs[24 + fj];
      float ig = sigm(vi), fg = sigm(vf), gg = tanh_f(vg), og = sigm(vo);
      float cn = fg * cs + ig * gg;
      cs = cn;
      htmp[fb][fj] = (_Float16)(og * tanh_f(cn));
    }
    __syncthreads();

    // ---- h store: write-through to LLC (agent atomics) ----
    if (tid < 128) {
      uint4 hv = *(const uint4*)&htmp[tid][0];
      st_h16_agent(hn + (size_t)(B0 + tid) * TH + 8 * wcg, hv);
    }
    __threadfence_block();   // drain own vmcnt: stores visible at LLC
    __syncthreads();         // whole block drained

    // ---- barrier arrival (relaxed: data already at LLC) ----
    if (tid == 0) {
      unsigned old = __hip_atomic_fetch_add(gcnt_grp, 1u, __ATOMIC_RELAXED, __HIP_MEMORY_SCOPE_AGENT);
      myLead = (old == (unsigned)(t + 1) * 16u - 1u);
    }

    // ---- out(t-1): waves 1..9, all 9 cols for this block's one batch ----
    if ((unsigned)(wv - 1) < 9u && t > 0) {
      const int r = wv - 1;
      const _Float16* hro = ha + (size_t)myb * TH + lane * 16;
      const float* wcp = Wc + r * 1024 + lane * 16;
      half8 h0v = *(const half8*)(hro);
      half8 h1v = *(const half8*)(hro + 8);
      float s = 0.f;
#pragma unroll
      for (int i = 0; i < 8; ++i)
        s += (float)h0v[i] * wcp[i] + (float)h1v[i] * wcp[8 + i];
#pragma unroll
      for (int off = 32; off > 0; off >>= 1) s += __shfl_down(s, off, 64);
      if (lane == 0) dout[((size_t)myb * TT + (t - 1)) * TOUT + r] = s + bco_s[r];
    }

    // ---- barrier spin (per-half tree; bounded; abort) + invalidate acquire ----
    if (tid == 0) {
      bool ab = false;
      unsigned guard = 0;
      if (myLead) {
        __hip_atomic_fetch_add(gcnt_root, 1u, __ATOMIC_RELAXED, __HIP_MEMORY_SCOPE_AGENT);
        while (__hip_atomic_load(gcnt_root, __ATOMIC_RELAXED, __HIP_MEMORY_SCOPE_AGENT) < (unsigned)(t + 1) * 8u) {
          __builtin_amdgcn_s_sleep(1);
          if (((++guard) & 255u) == 0u &&
              __hip_atomic_load(gabort, __ATOMIC_RELAXED, __HIP_MEMORY_SCOPE_AGENT) != 0u) { ab = true; break; }
          if (guard > 200000u) {
            __hip_atomic_store(gabort, 1u, __ATOMIC_RELAXED, __HIP_MEMORY_SCOPE_AGENT);
            ab = true; break;
          }
        }
        if (!ab) __hip_atomic_store(grel, (unsigned)(t + 1), __ATOMIC_RELAXED, __HIP_MEMORY_SCOPE_AGENT);
      } else {
        while (__hip_atomic_load(grel, __ATOMIC_RELAXED, __HIP_MEMORY_SCOPE_AGENT) < (unsigned)(t + 1)) {
          __builtin_amdgcn_s_sleep(1);
          if (((++guard) & 255u) == 0u &&
              __hip_atomic_load(gabort, __ATOMIC_RELAXED, __HIP_MEMORY_SCOPE_AGENT) != 0u) { ab = true; break; }
          if (guard > 200000u) {
            __hip_atomic_store(gabort, 1u, __ATOMIC_RELAXED, __HIP_MEMORY_SCOPE_AGENT);
            ab = true; break;
          }
        }
      }
      if (ab) {
        sAbort = 1;
      } else {
        // ACQUIRE load: emits buffer_inv (invalidate stale L1/L2), no wbl2.
        (void)__hip_atomic_load(grel, __ATOMIC_ACQUIRE, __HIP_MEMORY_SCOPE_AGENT);
      }
    }
    __syncthreads();
    if (sAbort) return;   // wrong answer beats a wedged GPU

    const _Float16* tp = ha; ha = hn; hn = (_Float16*)tp;
  }

  // ---- epilogue: out(TT-1) for this block's batch from final h ----
  if ((unsigned)(wv - 1) < 9u) {
    const int r = wv - 1;
    const _Float16* hro = ha + (size_t)myb * TH + lane * 16;
    const float* wcp = Wc + r * 1024 + lane * 16;
    half8 h0v = *(const half8*)(hro);
    half8 h1v = *(const half8*)(hro + 8);
    float s = 0.f;
#pragma unroll
    for (int i = 0; i < 8; ++i)
      s += (float)h0v[i] * wcp[i] + (float)h1v[i] * wcp[8 + i];
#pragma unroll
    for (int off = 32; off > 0; off >>= 1) s += __shfl_down(s, off, 64);
    if (lane == 0) dout[((size_t)myb * TT + (TT - 1)) * TOUT + r] = s + bco_s[r];
  }
}

// ---------------- launch ----------------

extern "C" void kernel_launch(void* const* d_in, const int* in_sizes, int n_in,
                              void* d_out, int out_size, void* d_ws, size_t ws_size,
                              hipStream_t stream) {
  if (ws_size < OB_END) return;   // clean fail, no OOB

  const float* x     = (const float*)d_in[0];
  const float* W_ih  = (const float*)d_in[1];
  const float* b_ih  = (const float*)d_in[2];
  const float* W_hh  = (const float*)d_in[3];
  const float* b_hh  = (const float*)d_in[4];
  const float* W_h2h = (const float*)d_in[5];
  const float* b_h2h = (const float*)d_in[6];
  const float* W_h2o = (const float*)d_in[7];
  const float* b_h2o = (const float*)d_in[8];
  const int*   lens  = (const int*)d_in[9];

  char* ws = (char*)d_ws;
  float* dout    = (float*)d_out;
  _Float16* Whf  = (_Float16*)(ws + OB_WHF);
  float* Wcombo  = (float*)(ws + OB_WCB);
  float* bcombo  = (float*)(ws + OB_BCB);
  float* b0      = (float*)(ws + OB_B0);
  float* bconst  = (float*)(ws + OB_BC);
  _Float16* h0   = (_Float16*)(ws + OB_H0);
  _Float16* h1   = (_Float16*)(ws + OB_H1);
  unsigned* gs   = (unsigned*)(ws + OB_GC);

  // zero h ping-pong + barrier counters every call (graph-replay safe)
  hipMemsetAsync((void*)(ws + OB_H0), 0, OB_END - OB_H0, stream);

  k_combo<<<36, 256, 0, stream>>>(W_h2o, W_h2h, b_h2h, b_h2o, Wcombo, bcombo);
  k_wblk<<<1024, 256, 0, stream>>>(W_hh, W_ih, W_h2o, W_h2h, Whf);
  k_bias<<<16, 256, 0, stream>>>(b_ih, b_hh, W_hh, W_ih, b_h2h, bcombo, b0, bconst);
  k_fillx<<<2048, 256, 0, stream>>>(W_ih, Whf);
  k_len<<<1, 256, 0, stream>>>(lens, dout);

  k_main<<<256, 1024, 0, stream>>>(x, Whf, Wcombo, b0, bconst, bcombo, h0, h1, gs, dout);
}

// Round 11
// 7518.773 us; speedup vs baseline: 1.0013x; 1.0013x over previous
//
#include <hip/hip_runtime.h>
#include <math.h>

#define TB 256      // batch
#define TT 512      // timesteps
#define TIN 128     // input size
#define TH 1024     // hidden
#define TOUT 9      // output coords
#define KD 1152     // TIN + TH

typedef _Float16 half8 __attribute__((ext_vector_type(8)));
typedef float f32x4 __attribute__((ext_vector_type(4)));

// ---- workspace layout (BYTE offsets) ----
#define OB_WHF   0ull
#define SB_WHF   (128ull*2*36*64*8*2)   // 9,437,184 B  f16 B-fragments [wcg][nt][kc][l][j]
#define OB_WCB   (OB_WHF + SB_WHF)      // Wcombo fp32 [9][1024]
#define SB_WCB   (9ull*1024*4)
#define OB_BCB   (OB_WCB + SB_WCB)      // bcombo fp32 [9] (pad 16)
#define SB_BCB   64ull
#define OB_B0    (OB_BCB + SB_BCB)      // bias t==0 [4096] fp32
#define SB_B0    (4096ull*4)
#define OB_BC    (OB_B0 + SB_B0)        // bias t>0  [4096] fp32
#define SB_BC    (4096ull*4)
#define OB_H0    (OB_BC + SB_BC)        // h_cell ping [256][1024] f16
#define SB_H     (256ull*1024*2)
#define OB_H1    (OB_H0 + SB_H)         // h_cell pong
#define OB_GC    (OB_H1 + SB_H)         // barrier counters (two halves, 128B lines)
#define OB_END   (OB_GC + 8192ull)      // ~10.5 MB total

// fragment address for gate col `col` (0..4095), k (0..1151):
//   q=col>>10 (gate), hcol=col&1023, wcg=hcol>>3, jj=hcol&7, c=(q<<3)|jj,
//   nt=c>>4, n=c&15, kc=k>>5, ls=(k>>3)&3, je=k&7, lane=(ls<<4)|n
__device__ __forceinline__ size_t frag_addr(int col, int k) {
  int q = col >> 10, hcol = col & 1023;
  int wcg = hcol >> 3, jj = hcol & 7;
  int c = (q << 3) | jj;
  int nt = c >> 4, n = c & 15;
  int kc = k >> 5, ls = (k >> 3) & 3, je = k & 7;
  return ((((size_t)wcg * 2 + nt) * 36 + kc) * 64 + ((ls << 4) | n)) * 8 + je;
}

// ---- agent-scope (LLC write-through) 16B h store as 2x8B relaxed atomics ----
__device__ __forceinline__ void st_h16_agent(_Float16* p, uint4 v) {
  union { uint4 q; unsigned long long u[2]; } c; c.q = v;
  __hip_atomic_store((unsigned long long*)p,     c.u[0], __ATOMIC_RELAXED, __HIP_MEMORY_SCOPE_AGENT);
  __hip_atomic_store((unsigned long long*)p + 1, c.u[1], __ATOMIC_RELAXED, __HIP_MEMORY_SCOPE_AGENT);
}

// ---------------- prep kernels (unchanged, verified rounds 5-10) ----------------

__global__ __launch_bounds__(256) void k_combo(const float* __restrict__ W_h2o,
                                               const float* __restrict__ W_h2h,
                                               const float* __restrict__ b_h2h,
                                               const float* __restrict__ b_h2o,
                                               float* __restrict__ Wcombo,
                                               float* __restrict__ bcombo) {
  int gid = blockIdx.x * 256 + threadIdx.x;
  if (gid < 9 * 1024) {
    int r = gid >> 10, m = gid & 1023;
    float s = 0.f;
    for (int j = 0; j < 1024; ++j) s += W_h2o[r * 1024 + j] * W_h2h[j * 1024 + m];
    Wcombo[gid] = s;
  }
  if (gid < 9) {
    float s = b_h2o[gid];
    for (int j = 0; j < 1024; ++j) s += W_h2o[gid * 1024 + j] * b_h2h[j];
    bcombo[gid] = s;
  }
}

__global__ __launch_bounds__(256) void k_wblk(const float* __restrict__ W_hh,
                                              const float* __restrict__ W_ih,
                                              const float* __restrict__ W_h2o,
                                              const float* __restrict__ W_h2h,
                                              _Float16* __restrict__ Whf) {
  __shared__ float As2[16][68];
  __shared__ float Bs[16][68];
  __shared__ float Wio_s[64][12];
  __shared__ float Bo[9][16];
  const int tid = threadIdx.x;
  const int bm = (blockIdx.x & 15) * 64;   // m tile
  const int bc = (blockIdx.x >> 4) * 64;   // col tile
  const int tx = tid & 15, ty = tid >> 4;
  const int cl = tid >> 2, kq4 = tid & 3;

  for (int i = tid; i < 64 * 9; i += 256) {
    int row = i / 9, r = i % 9;
    Wio_s[row][r] = W_ih[(size_t)(bc + row) * 137 + 128 + r];
  }

  float acc[4][4];
#pragma unroll
  for (int i = 0; i < 4; ++i)
#pragma unroll
    for (int j = 0; j < 4; ++j) acc[i][j] = 0.f;

  for (int k0 = 0; k0 < 1024; k0 += 16) {
    __syncthreads();
    if (tid < 144) { int r = tid >> 4, kk = tid & 15; Bo[r][kk] = W_h2o[(size_t)r * 1024 + k0 + kk]; }
    { int kk = tid >> 4, q = tid & 15;
      float4 v = *(const float4*)(W_h2h + (size_t)(k0 + kk) * 1024 + bm + q * 4);
      *(float4*)&Bs[kk][q * 4] = v; }
    float4 av = *(const float4*)(W_hh + (size_t)(bc + cl) * 1024 + k0 + kq4 * 4);
    __syncthreads();
    {
      float c0 = 0.f, c1 = 0.f, c2 = 0.f, c3 = 0.f;
#pragma unroll
      for (int r = 0; r < 9; ++r) {
        float wio = Wio_s[cl][r];
        c0 += wio * Bo[r][kq4 * 4 + 0];
        c1 += wio * Bo[r][kq4 * 4 + 1];
        c2 += wio * Bo[r][kq4 * 4 + 2];
        c3 += wio * Bo[r][kq4 * 4 + 3];
      }
      As2[kq4 * 4 + 0][cl] = av.x + c0;
      As2[kq4 * 4 + 1][cl] = av.y + c1;
      As2[kq4 * 4 + 2][cl] = av.z + c2;
      As2[kq4 * 4 + 3][cl] = av.w + c3;
    }
    __syncthreads();
#pragma unroll
    for (int kk = 0; kk < 16; ++kk) {
      float4 a = *(const float4*)&As2[kk][ty * 4];
      float4 bv = *(const float4*)&Bs[kk][tx * 4];
      acc[0][0] += a.x * bv.x; acc[0][1] += a.x * bv.y; acc[0][2] += a.x * bv.z; acc[0][3] += a.x * bv.w;
      acc[1][0] += a.y * bv.x; acc[1][1] += a.y * bv.y; acc[1][2] += a.y * bv.z; acc[1][3] += a.y * bv.w;
      acc[2][0] += a.z * bv.x; acc[2][1] += a.z * bv.y; acc[2][2] += a.z * bv.z; acc[2][3] += a.z * bv.w;
      acc[3][0] += a.w * bv.x; acc[3][1] += a.w * bv.y; acc[3][2] += a.w * bv.z; acc[3][3] += a.w * bv.w;
    }
  }
#pragma unroll
  for (int i = 0; i < 4; ++i)
#pragma unroll
    for (int j = 0; j < 4; ++j) {
      int col = bc + ty * 4 + i;          // gate col
      int m = bm + tx * 4 + j;            // h index -> k = 128+m
      Whf[frag_addr(col, 128 + m)] = (_Float16)acc[i][j];
    }
}

__global__ __launch_bounds__(256) void k_bias(const float* __restrict__ b_ih,
                                              const float* __restrict__ b_hh,
                                              const float* __restrict__ W_hh,
                                              const float* __restrict__ W_ih,
                                              const float* __restrict__ b_h2h,
                                              const float* __restrict__ bcombo,
                                              float* __restrict__ b0,
                                              float* __restrict__ bconst) {
  int col = blockIdx.x * 256 + threadIdx.x;
  float base = b_ih[col] + b_hh[col];
  b0[col] = base;
  float s = 0.f;
  for (int j = 0; j < 1024; ++j) s += W_hh[(size_t)col * 1024 + j] * b_h2h[j];
#pragma unroll
  for (int r = 0; r < 9; ++r) s += W_ih[(size_t)col * 137 + 128 + r] * bcombo[r];
  bconst[col] = base + s;
}

__global__ __launch_bounds__(256) void k_fillx(const float* __restrict__ W_ih,
                                               _Float16* __restrict__ Whf) {
  int gid = blockIdx.x * 256 + threadIdx.x;   // 4096*128
  int col = gid >> 7, k = gid & 127;
  Whf[frag_addr(col, k)] = (_Float16)W_ih[(size_t)col * 137 + k];
}

__global__ void k_len(const int* __restrict__ len, float* __restrict__ dout) {
  int i = threadIdx.x;
  if (i < TB) dout[(size_t)TB * TT * TOUT + i] = (float)len[i];
}

// ---------------- persistent main kernel ----------------
// 256 blocks x 512 thr (8 waves, 2/SIMD). Block = (half_id, wcg). Waves:
// kh = wv>>2 (K-half), mp = wv&3 (M-pair: 2 M-tiles of 16 batches). Each wave
// computes 2M x 2N per B-read -> 288 ds_read_b128/CU/step (halved vs r10).
// A-fragments (36 half8/wave) force-prefetched via keep-alive asm + sched
// barrier -> one vmcnt drain. Wc staged to LDS (no post-inv refetch).
// Barrier: group RMW -> root RMW, ALL tid0s poll root directly (no release
// hop), bounded spin + abort. h: write-through agent atomics + cached reads
// + invalidate-only ACQUIRE per block per step (proven r8-r10).

__device__ __forceinline__ float sigm(float v) { return 1.f / (1.f + __expf(-v)); }
__device__ __forceinline__ float tanh_f(float v) {
  float e2 = __expf(2.f * v);
  return (e2 - 1.f) / (e2 + 1.f);
}

#define KEEP18(a) asm volatile("" :: "v"(a[0]), "v"(a[1]), "v"(a[2]), "v"(a[3]), \
  "v"(a[4]), "v"(a[5]), "v"(a[6]), "v"(a[7]), "v"(a[8]), "v"(a[9]), "v"(a[10]), \
  "v"(a[11]), "v"(a[12]), "v"(a[13]), "v"(a[14]), "v"(a[15]), "v"(a[16]), "v"(a[17]))

__global__ __launch_bounds__(512, 2) void k_main(const float* __restrict__ x,
                                                 const _Float16* __restrict__ Whf,
                                                 const float* __restrict__ Wc,
                                                 const float* __restrict__ b0,
                                                 const float* __restrict__ bcf,
                                                 const float* __restrict__ bcombo,
                                                 _Float16* __restrict__ hA,
                                                 _Float16* __restrict__ hB,
                                                 unsigned* __restrict__ gs,
                                                 float* __restrict__ dout) {
  __shared__ _Float16 Wl[2 * 36 * 64 * 8];   // 73,728 B
  __shared__ float gbuf[2][128][36];         // 36,864 B (K-half partials)
  __shared__ float Wc_s[9][1024];            // 36,864 B out weights
  __shared__ _Float16 htmp[128][8];          //  2,048 B
  __shared__ float bias_s[2][32];
  __shared__ float bco_s[12];
  __shared__ int sAbort;

  const int bx = blockIdx.x;
  const int half_id = bx >> 7;       // 0/1: independent batch-half
  const int wcg = bx & 127;          // col-group: h-cols 8*wcg..+7
  const int B0 = half_id * 128;      // batch base
  const int myb = B0 + wcg;          // this block's out-GEMV batch
  const int grp = wcg >> 4;          // barrier group within half (8 groups x 16)
  const int tid = threadIdx.x;
  const int lane = tid & 63;
  const int wv = tid >> 6;           // 0..7
  const int mp = wv & 3, kh = wv >> 2;

  unsigned* hbase = gs + half_id * 1024;     // per-half barrier region
  unsigned* gcnt_grp = hbase + grp * 32;     // arrival counter (own 128B line)
  unsigned* gcnt_root = hbase + 8 * 32;      // root counter (8 leads)
  unsigned* gabort = gs + 1984;              // global abort flag (shared)

  {  // stage W fragments once (reused 512 steps)
    const uint4* src = (const uint4*)(Whf + (size_t)wcg * (2 * 36 * 64 * 8));
    uint4* dst = (uint4*)Wl;
    for (int i = tid; i < 2 * 36 * 64 * 8 / 8; i += 512) dst[i] = src[i];
  }
  {  // stage Wc (9x1024 fp32) once
    const float4* src = (const float4*)Wc;
    float4* dst = (float4*)&Wc_s[0][0];
    for (int i = tid; i < 9 * 1024 / 4; i += 512) dst[i] = src[i];
  }
  if (tid == 0) sAbort = 0;
  if (tid < 9) bco_s[tid] = bcombo[tid];
  if (tid < 32) {
    int g = (tid >> 3) * 1024 + wcg * 8 + (tid & 7);   // c=(q<<3)|jj -> gate col
    bias_s[0][tid] = b0[g];
    bias_s[1][tid] = bcf[g];
  }
  float cs0 = 0.f, cs1 = 0.f;   // cell states: (tid>>3, tid&7), (64+(tid>>3), tid&7)
  __syncthreads();

  const _Float16* ha = hA;   // h_cell(t-1), zeroed by memset
  _Float16* hn = hB;

  const int bA0 = B0 + mp * 32 + (lane & 15);  // A row, M-tile 0 of pair
  const int bA1 = bA0 + 16;                    // A row, M-tile 1 of pair
  const int ko = (lane >> 4) * 8;              // A k offset within 32-chunk
  const _Float16* wlb = Wl + (size_t)lane * 8 + (size_t)(kh * 18) * 512;
  unsigned myLead = 0;

  for (int t = 0; t < TT; ++t) {
    // ---- A-fragment prefetch: 36 loads issued, pinned live via asm ----
    const _Float16* h0row = ha + (size_t)bA0 * TH;
    const _Float16* h1row = ha + (size_t)bA1 * TH;
    half8 a0[18], a1[18];
    if (kh == 0) {
      const float* x0 = x + ((size_t)bA0 * TT + t) * TIN;
      const float* x1 = x + ((size_t)bA1 * TT + t) * TIN;
      float4 xv0[8], xv1[8];
#pragma unroll
      for (int i = 0; i < 4; ++i) {
        xv0[2 * i]     = *(const float4*)(x0 + i * 32 + ko);
        xv0[2 * i + 1] = *(const float4*)(x0 + i * 32 + ko + 4);
        xv1[2 * i]     = *(const float4*)(x1 + i * 32 + ko);
        xv1[2 * i + 1] = *(const float4*)(x1 + i * 32 + ko + 4);
      }
#pragma unroll
      for (int lc = 4; lc < 18; ++lc) {
        a0[lc] = *(const half8*)(h0row + (lc * 32 - 128 + ko));
        a1[lc] = *(const half8*)(h1row + (lc * 32 - 128 + ko));
      }
#pragma unroll
      for (int i = 0; i < 4; ++i) {
        half8 v0, v1;
        v0[0] = (_Float16)xv0[2 * i].x; v0[1] = (_Float16)xv0[2 * i].y;
        v0[2] = (_Float16)xv0[2 * i].z; v0[3] = (_Float16)xv0[2 * i].w;
        v0[4] = (_Float16)xv0[2 * i + 1].x; v0[5] = (_Float16)xv0[2 * i + 1].y;
        v0[6] = (_Float16)xv0[2 * i + 1].z; v0[7] = (_Float16)xv0[2 * i + 1].w;
        v1[0] = (_Float16)xv1[2 * i].x; v1[1] = (_Float16)xv1[2 * i].y;
        v1[2] = (_Float16)xv1[2 * i].z; v1[3] = (_Float16)xv1[2 * i].w;
        v1[4] = (_Float16)xv1[2 * i + 1].x; v1[5] = (_Float16)xv1[2 * i + 1].y;
        v1[6] = (_Float16)xv1[2 * i + 1].z; v1[7] = (_Float16)xv1[2 * i + 1].w;
        a0[i] = v0; a1[i] = v1;
      }
    } else {
#pragma unroll
      for (int lc = 0; lc < 18; ++lc) {
        a0[lc] = *(const half8*)(h0row + ((18 + lc) * 32 - 128 + ko));
        a1[lc] = *(const half8*)(h1row + ((18 + lc) * 32 - 128 + ko));
      }
    }
    KEEP18(a0);          // data dep: all a0 values must be in registers here
    KEEP18(a1);          // same for a1 -> loads can't sink into MFMA loop
    __builtin_amdgcn_sched_barrier(0);

    // ---- MFMA loop: 2 LDS reads feed 4 MFMAs (2M x 2N) ----
    f32x4 acc00 = {0.f, 0.f, 0.f, 0.f};
    f32x4 acc01 = {0.f, 0.f, 0.f, 0.f};
    f32x4 acc10 = {0.f, 0.f, 0.f, 0.f};
    f32x4 acc11 = {0.f, 0.f, 0.f, 0.f};
#pragma unroll
    for (int lc = 0; lc < 18; ++lc) {
      half8 bf0 = *(const half8*)(wlb + (size_t)lc * 512);
      half8 bf1 = *(const half8*)(wlb + (size_t)(36 + lc) * 512);
      acc00 = __builtin_amdgcn_mfma_f32_16x16x32_f16(a0[lc], bf0, acc00, 0, 0, 0);
      acc01 = __builtin_amdgcn_mfma_f32_16x16x32_f16(a0[lc], bf1, acc01, 0, 0, 0);
      acc10 = __builtin_amdgcn_mfma_f32_16x16x32_f16(a1[lc], bf0, acc10, 0, 0, 0);
      acc11 = __builtin_amdgcn_mfma_f32_16x16x32_f16(a1[lc], bf1, acc11, 0, 0, 0);
    }
    {  // D layout: col = lane&15, row = (lane>>4)*4 + r
      int rb0 = mp * 32 + (lane >> 4) * 4;
      int rb1 = rb0 + 16;
      int cc = lane & 15;
#pragma unroll
      for (int r = 0; r < 4; ++r) {
        gbuf[kh][rb0 + r][cc] = acc00[r];
        gbuf[kh][rb0 + r][16 + cc] = acc01[r];
        gbuf[kh][rb1 + r][cc] = acc10[r];
        gbuf[kh][rb1 + r][16 + cc] = acc11[r];
      }
    }
    __syncthreads();

    // ---- LSTM finish: 512 threads x 2 gate-sets; cs in registers ----
    {
      const int fb = tid >> 3, fj = tid & 7;   // set A: batch fb; set B: fb+64
      const float* bs = bias_s[(t > 0) ? 1 : 0];
      float vi = gbuf[0][fb][fj]      + gbuf[1][fb][fj]      + bs[fj];
      float vf = gbuf[0][fb][8 + fj]  + gbuf[1][fb][8 + fj]  + bs[8 + fj];
      float vg = gbuf[0][fb][16 + fj] + gbuf[1][fb][16 + fj] + bs[16 + fj];
      float vo = gbuf[0][fb][24 + fj] + gbuf[1][fb][24 + fj] + bs[24 + fj];
      float ig = sigm(vi), fg = sigm(vf), gg = tanh_f(vg), og = sigm(vo);
      float cn = fg * cs0 + ig * gg;
      cs0 = cn;
      htmp[fb][fj] = (_Float16)(og * tanh_f(cn));

      const int fb2 = fb + 64;
      float vi2 = gbuf[0][fb2][fj]      + gbuf[1][fb2][fj]      + bs[fj];
      float vf2 = gbuf[0][fb2][8 + fj]  + gbuf[1][fb2][8 + fj]  + bs[8 + fj];
      float vg2 = gbuf[0][fb2][16 + fj] + gbuf[1][fb2][16 + fj] + bs[16 + fj];
      float vo2 = gbuf[0][fb2][24 + fj] + gbuf[1][fb2][24 + fj] + bs[24 + fj];
      float ig2 = sigm(vi2), fg2 = sigm(vf2), gg2 = tanh_f(vg2), og2 = sigm(vo2);
      float cn2 = fg2 * cs1 + ig2 * gg2;
      cs1 = cn2;
      htmp[fb2][fj] = (_Float16)(og2 * tanh_f(cn2));
    }
    __syncthreads();

    // ---- h store: write-through to LLC (agent atomics) ----
    if (tid < 128) {
      uint4 hv = *(const uint4*)&htmp[tid][0];
      st_h16_agent(hn + (size_t)(B0 + tid) * TH + 8 * wcg, hv);
    }
    __threadfence_block();   // drain own vmcnt: stores visible at LLC
    __syncthreads();         // whole block drained

    // ---- barrier arrival; leads bump root ----
    if (tid == 0) {
      unsigned old = __hip_atomic_fetch_add(gcnt_grp, 1u, __ATOMIC_RELAXED, __HIP_MEMORY_SCOPE_AGENT);
      myLead = (old == (unsigned)(t + 1) * 16u - 1u);
      if (myLead)
        __hip_atomic_fetch_add(gcnt_root, 1u, __ATOMIC_RELAXED, __HIP_MEMORY_SCOPE_AGENT);
    }

    // ---- out(t-1): wave wv -> col wv (wave 0 also col 8), one batch ----
    if (t > 0) {
      const _Float16* hro = ha + (size_t)myb * TH;
      {
        const float* wrow = &Wc_s[wv][0];
        float s = 0.f;
#pragma unroll
        for (int j = 0; j < 16; ++j) {
          int idx = lane + j * 64;
          s += (float)hro[idx] * wrow[idx];
        }
#pragma unroll
        for (int off = 32; off > 0; off >>= 1) s += __shfl_down(s, off, 64);
        if (lane == 0) dout[((size_t)myb * TT + (t - 1)) * TOUT + wv] = s + bco_s[wv];
      }
      if (wv == 0) {
        const float* wrow = &Wc_s[8][0];
        float s = 0.f;
#pragma unroll
        for (int j = 0; j < 16; ++j) {
          int idx = lane + j * 64;
          s += (float)hro[idx] * wrow[idx];
        }
#pragma unroll
        for (int off = 32; off > 0; off >>= 1) s += __shfl_down(s, off, 64);
        if (lane == 0) dout[((size_t)myb * TT + (t - 1)) * TOUT + 8] = s + bco_s[8];
      }
    }

    // ---- barrier: ALL tid0s poll root directly (bounded; abort) + inv ----
    if (tid == 0) {
      bool ab = false;
      unsigned guard = 0;
      const unsigned tgt = (unsigned)(t + 1) * 8u;
      while (__hip_atomic_load(gcnt_root, __ATOMIC_RELAXED, __HIP_MEMORY_SCOPE_AGENT) < tgt) {
        __builtin_amdgcn_s_sleep(1);
        if (((++guard) & 255u) == 0u &&
            __hip_atomic_load(gabort, __ATOMIC_RELAXED, __HIP_MEMORY_SCOPE_AGENT) != 0u) { ab = true; break; }
        if (guard > 200000u) {
          __hip_atomic_store(gabort, 1u, __ATOMIC_RELAXED, __HIP_MEMORY_SCOPE_AGENT);
          ab = true; break;
        }
      }
      if (ab) {
        sAbort = 1;
      } else {
        // ACQUIRE load: emits buffer_inv (invalidate stale L1/L2), no wbl2.
        (void)__hip_atomic_load(gcnt_root, __ATOMIC_ACQUIRE, __HIP_MEMORY_SCOPE_AGENT);
      }
    }
    __syncthreads();
    if (sAbort) return;   // wrong answer beats a wedged GPU

    const _Float16* tp = ha; ha = hn; hn = (_Float16*)tp;
  }

  // ---- epilogue: out(TT-1) for this block's batch from final h ----
  {
    const _Float16* hro = ha + (size_t)myb * TH;
    {
      const float* wrow = &Wc_s[wv][0];
      float s = 0.f;
#pragma unroll
      for (int j = 0; j < 16; ++j) {
        int idx = lane + j * 64;
        s += (float)hro[idx] * wrow[idx];
      }
#pragma unroll
      for (int off = 32; off > 0; off >>= 1) s += __shfl_down(s, off, 64);
      if (lane == 0) dout[((size_t)myb * TT + (TT - 1)) * TOUT + wv] = s + bco_s[wv];
    }
    if (wv == 0) {
      const float* wrow = &Wc_s[8][0];
      float s = 0.f;
#pragma unroll
      for (int j = 0; j < 16; ++j) {
        int idx = lane + j * 64;
        s += (float)hro[idx] * wrow[idx];
      }
#pragma unroll
      for (int off = 32; off > 0; off >>= 1) s += __shfl_down(s, off, 64);
      if (lane == 0) dout[((size_t)myb * TT + (TT - 1)) * TOUT + 8] = s + bco_s[8];
    }
  }
}

// ---------------- launch ----------------

extern "C" void kernel_launch(void* const* d_in, const int* in_sizes, int n_in,
                              void* d_out, int out_size, void* d_ws, size_t ws_size,
                              hipStream_t stream) {
  if (ws_size < OB_END) return;   // clean fail, no OOB

  const float* x     = (const float*)d_in[0];
  const float* W_ih  = (const float*)d_in[1];
  const float* b_ih  = (const float*)d_in[2];
  const float* W_hh  = (const float*)d_in[3];
  const float* b_hh  = (const float*)d_in[4];
  const float* W_h2h = (const float*)d_in[5];
  const float* b_h2h = (const float*)d_in[6];
  const float* W_h2o = (const float*)d_in[7];
  const float* b_h2o = (const float*)d_in[8];
  const int*   lens  = (const int*)d_in[9];

  char* ws = (char*)d_ws;
  float* dout    = (float*)d_out;
  _Float16* Whf  = (_Float16*)(ws + OB_WHF);
  float* Wcombo  = (float*)(ws + OB_WCB);
  float* bcombo  = (float*)(ws + OB_BCB);
  float* b0      = (float*)(ws + OB_B0);
  float* bconst  = (float*)(ws + OB_BC);
  _Float16* h0   = (_Float16*)(ws + OB_H0);
  _Float16* h1   = (_Float16*)(ws + OB_H1);
  unsigned* gs   = (unsigned*)(ws + OB_GC);

  // zero h ping-pong + barrier counters every call (graph-replay safe)
  hipMemsetAsync((void*)(ws + OB_H0), 0, OB_END - OB_H0, stream);

  k_combo<<<36, 256, 0, stream>>>(W_h2o, W_h2h, b_h2h, b_h2o, Wcombo, bcombo);
  k_wblk<<<1024, 256, 0, stream>>>(W_hh, W_ih, W_h2o, W_h2h, Whf);
  k_bias<<<16, 256, 0, stream>>>(b_ih, b_hh, W_hh, W_ih, b_h2h, bcombo, b0, bconst);
  k_fillx<<<2048, 256, 0, stream>>>(W_ih, Whf);
  k_len<<<1, 256, 0, stream>>>(lens, dout);

  k_main<<<256, 512, 0, stream>>>(x, Whf, Wcombo, b0, bconst, bcombo, h0, h1, gs, dout);
}

// Round 12
// 5459.669 us; speedup vs baseline: 1.3790x; 1.3771x over previous
//
#include <hip/hip_runtime.h>
#include <math.h>

#define TB 256      // batch
#define TT 512      // timesteps
#define TIN 128     // input size
#define TH 1024     // hidden
#define TOUT 9      // output coords
#define KD 1152     // TIN + TH

typedef _Float16 half8 __attribute__((ext_vector_type(8)));
typedef float f32x4 __attribute__((ext_vector_type(4)));

// ---- workspace layout (BYTE offsets) ----
#define OB_WHF   0ull
#define SB_WHF   (128ull*2*36*64*8*2)   // 9,437,184 B  f16 B-fragments [wcg][nt][kc][l][j]
#define OB_WCB   (OB_WHF + SB_WHF)      // Wcombo fp32 [9][1024]
#define SB_WCB   (9ull*1024*4)
#define OB_BCB   (OB_WCB + SB_WCB)      // bcombo fp32 [9] (pad 16)
#define SB_BCB   64ull
#define OB_B0    (OB_BCB + SB_BCB)      // bias t==0 [4096] fp32
#define SB_B0    (4096ull*4)
#define OB_BC    (OB_B0 + SB_B0)        // bias t>0  [4096] fp32
#define SB_BC    (4096ull*4)
#define OB_H0    (OB_BC + SB_BC)        // hx ping [128 chunk][256 b][8] f16 (chunk-major!)
#define SB_H     (256ull*1024*2)
#define OB_H1    (OB_H0 + SB_H)         // hx pong
#define OB_GC    (OB_H1 + SB_H)         // barrier counters (two halves, 128B lines)
#define OB_END   (OB_GC + 8192ull)      // ~10.5 MB total

// fragment address for gate col `col` (0..4095), k (0..1151):
//   q=col>>10 (gate), hcol=col&1023, wcg=hcol>>3, jj=hcol&7, c=(q<<3)|jj,
//   nt=c>>4, n=c&15, kc=k>>5, ls=(k>>3)&3, je=k&7, lane=(ls<<4)|n
__device__ __forceinline__ size_t frag_addr(int col, int k) {
  int q = col >> 10, hcol = col & 1023;
  int wcg = hcol >> 3, jj = hcol & 7;
  int c = (q << 3) | jj;
  int nt = c >> 4, n = c & 15;
  int kc = k >> 5, ls = (k >> 3) & 3, je = k & 7;
  return ((((size_t)wcg * 2 + nt) * 36 + kc) * 64 + ((ls << 4) | n)) * 8 + je;
}

// ---- agent-scope (LLC write-through) 16B h store as 2x8B relaxed atomics ----
__device__ __forceinline__ void st_h16_agent(_Float16* p, uint4 v) {
  union { uint4 q; unsigned long long u[2]; } c; c.q = v;
  __hip_atomic_store((unsigned long long*)p,     c.u[0], __ATOMIC_RELAXED, __HIP_MEMORY_SCOPE_AGENT);
  __hip_atomic_store((unsigned long long*)p + 1, c.u[1], __ATOMIC_RELAXED, __HIP_MEMORY_SCOPE_AGENT);
}

// ---------------- prep kernels (unchanged, verified rounds 5-11) ----------------

__global__ __launch_bounds__(256) void k_combo(const float* __restrict__ W_h2o,
                                               const float* __restrict__ W_h2h,
                                               const float* __restrict__ b_h2h,
                                               const float* __restrict__ b_h2o,
                                               float* __restrict__ Wcombo,
                                               float* __restrict__ bcombo) {
  int gid = blockIdx.x * 256 + threadIdx.x;
  if (gid < 9 * 1024) {
    int r = gid >> 10, m = gid & 1023;
    float s = 0.f;
    for (int j = 0; j < 1024; ++j) s += W_h2o[r * 1024 + j] * W_h2h[j * 1024 + m];
    Wcombo[gid] = s;
  }
  if (gid < 9) {
    float s = b_h2o[gid];
    for (int j = 0; j < 1024; ++j) s += W_h2o[gid * 1024 + j] * b_h2h[j];
    bcombo[gid] = s;
  }
}

__global__ __launch_bounds__(256) void k_wblk(const float* __restrict__ W_hh,
                                              const float* __restrict__ W_ih,
                                              const float* __restrict__ W_h2o,
                                              const float* __restrict__ W_h2h,
                                              _Float16* __restrict__ Whf) {
  __shared__ float As2[16][68];
  __shared__ float Bs[16][68];
  __shared__ float Wio_s[64][12];
  __shared__ float Bo[9][16];
  const int tid = threadIdx.x;
  const int bm = (blockIdx.x & 15) * 64;   // m tile
  const int bc = (blockIdx.x >> 4) * 64;   // col tile
  const int tx = tid & 15, ty = tid >> 4;
  const int cl = tid >> 2, kq4 = tid & 3;

  for (int i = tid; i < 64 * 9; i += 256) {
    int row = i / 9, r = i % 9;
    Wio_s[row][r] = W_ih[(size_t)(bc + row) * 137 + 128 + r];
  }

  float acc[4][4];
#pragma unroll
  for (int i = 0; i < 4; ++i)
#pragma unroll
    for (int j = 0; j < 4; ++j) acc[i][j] = 0.f;

  for (int k0 = 0; k0 < 1024; k0 += 16) {
    __syncthreads();
    if (tid < 144) { int r = tid >> 4, kk = tid & 15; Bo[r][kk] = W_h2o[(size_t)r * 1024 + k0 + kk]; }
    { int kk = tid >> 4, q = tid & 15;
      float4 v = *(const float4*)(W_h2h + (size_t)(k0 + kk) * 1024 + bm + q * 4);
      *(float4*)&Bs[kk][q * 4] = v; }
    float4 av = *(const float4*)(W_hh + (size_t)(bc + cl) * 1024 + k0 + kq4 * 4);
    __syncthreads();
    {
      float c0 = 0.f, c1 = 0.f, c2 = 0.f, c3 = 0.f;
#pragma unroll
      for (int r = 0; r < 9; ++r) {
        float wio = Wio_s[cl][r];
        c0 += wio * Bo[r][kq4 * 4 + 0];
        c1 += wio * Bo[r][kq4 * 4 + 1];
        c2 += wio * Bo[r][kq4 * 4 + 2];
        c3 += wio * Bo[r][kq4 * 4 + 3];
      }
      As2[kq4 * 4 + 0][cl] = av.x + c0;
      As2[kq4 * 4 + 1][cl] = av.y + c1;
      As2[kq4 * 4 + 2][cl] = av.z + c2;
      As2[kq4 * 4 + 3][cl] = av.w + c3;
    }
    __syncthreads();
#pragma unroll
    for (int kk = 0; kk < 16; ++kk) {
      float4 a = *(const float4*)&As2[kk][ty * 4];
      float4 bv = *(const float4*)&Bs[kk][tx * 4];
      acc[0][0] += a.x * bv.x; acc[0][1] += a.x * bv.y; acc[0][2] += a.x * bv.z; acc[0][3] += a.x * bv.w;
      acc[1][0] += a.y * bv.x; acc[1][1] += a.y * bv.y; acc[1][2] += a.y * bv.z; acc[1][3] += a.y * bv.w;
      acc[2][0] += a.z * bv.x; acc[2][1] += a.z * bv.y; acc[2][2] += a.z * bv.z; acc[2][3] += a.z * bv.w;
      acc[3][0] += a.w * bv.x; acc[3][1] += a.w * bv.y; acc[3][2] += a.w * bv.z; acc[3][3] += a.w * bv.w;
    }
  }
#pragma unroll
  for (int i = 0; i < 4; ++i)
#pragma unroll
    for (int j = 0; j < 4; ++j) {
      int col = bc + ty * 4 + i;          // gate col
      int m = bm + tx * 4 + j;            // h index -> k = 128+m
      Whf[frag_addr(col, 128 + m)] = (_Float16)acc[i][j];
    }
}

__global__ __launch_bounds__(256) void k_bias(const float* __restrict__ b_ih,
                                              const float* __restrict__ b_hh,
                                              const float* __restrict__ W_hh,
                                              const float* __restrict__ W_ih,
                                              const float* __restrict__ b_h2h,
                                              const float* __restrict__ bcombo,
                                              float* __restrict__ b0,
                                              float* __restrict__ bconst) {
  int col = blockIdx.x * 256 + threadIdx.x;
  float base = b_ih[col] + b_hh[col];
  b0[col] = base;
  float s = 0.f;
  for (int j = 0; j < 1024; ++j) s += W_hh[(size_t)col * 1024 + j] * b_h2h[j];
#pragma unroll
  for (int r = 0; r < 9; ++r) s += W_ih[(size_t)col * 137 + 128 + r] * bcombo[r];
  bconst[col] = base + s;
}

__global__ __launch_bounds__(256) void k_fillx(const float* __restrict__ W_ih,
                                               _Float16* __restrict__ Whf) {
  int gid = blockIdx.x * 256 + threadIdx.x;   // 4096*128
  int col = gid >> 7, k = gid & 127;
  Whf[frag_addr(col, k)] = (_Float16)W_ih[(size_t)col * 137 + k];
}

__global__ void k_len(const int* __restrict__ len, float* __restrict__ dout) {
  int i = threadIdx.x;
  if (i < TB) dout[(size_t)TB * TT * TOUT + i] = (float)len[i];
}

// ---------------- persistent main kernel ----------------
// 256 blocks x 512 thr (8 waves). Block = (half_id, wcg). Same structure as
// r11 EXCEPT the h exchange buffer is CHUNK-MAJOR: hx[chunk=col/8][batch][8].
// Block wcg writes hx[wcg][B0..B0+127][*] = 2 KB CONTIGUOUS (full 128B lines,
// no HBM sector RMW — r11's 4x write amplification came from 16B islands at
// 2KB stride). Reads are unchanged-coalesced: every A-fragment is one aligned
// 16B cell hx[K>>3][b][*]; 16 consecutive lanes -> 256B contiguous.

__device__ __forceinline__ float sigm(float v) { return 1.f / (1.f + __expf(-v)); }
__device__ __forceinline__ float tanh_f(float v) {
  float e2 = __expf(2.f * v);
  return (e2 - 1.f) / (e2 + 1.f);
}

#define KEEP18(a) asm volatile("" :: "v"(a[0]), "v"(a[1]), "v"(a[2]), "v"(a[3]), \
  "v"(a[4]), "v"(a[5]), "v"(a[6]), "v"(a[7]), "v"(a[8]), "v"(a[9]), "v"(a[10]), \
  "v"(a[11]), "v"(a[12]), "v"(a[13]), "v"(a[14]), "v"(a[15]), "v"(a[16]), "v"(a[17]))

__global__ __launch_bounds__(512, 2) void k_main(const float* __restrict__ x,
                                                 const _Float16* __restrict__ Whf,
                                                 const float* __restrict__ Wc,
                                                 const float* __restrict__ b0,
                                                 const float* __restrict__ bcf,
                                                 const float* __restrict__ bcombo,
                                                 _Float16* __restrict__ hA,
                                                 _Float16* __restrict__ hB,
                                                 unsigned* __restrict__ gs,
                                                 float* __restrict__ dout) {
  __shared__ _Float16 Wl[2 * 36 * 64 * 8];   // 73,728 B
  __shared__ float gbuf[2][128][36];         // 36,864 B (K-half partials)
  __shared__ float Wc_s[9][1024];            // 36,864 B out weights
  __shared__ _Float16 htmp[128][8];          //  2,048 B
  __shared__ float bias_s[2][32];
  __shared__ float bco_s[12];
  __shared__ int sAbort;

  const int bx = blockIdx.x;
  const int half_id = bx >> 7;       // 0/1: independent batch-half
  const int wcg = bx & 127;          // col-group: h-cols 8*wcg..+7 = chunk wcg
  const int B0 = half_id * 128;      // batch base
  const int myb = B0 + wcg;          // this block's out-GEMV batch
  const int grp = wcg >> 4;          // barrier group within half (8 groups x 16)
  const int tid = threadIdx.x;
  const int lane = tid & 63;
  const int wv = tid >> 6;           // 0..7
  const int mp = wv & 3, kh = wv >> 2;

  const size_t CH = (size_t)TB * 8;  // halves per chunk (256 batches x 8)

  unsigned* hbase = gs + half_id * 1024;     // per-half barrier region
  unsigned* gcnt_grp = hbase + grp * 32;     // arrival counter (own 128B line)
  unsigned* gcnt_root = hbase + 8 * 32;      // root counter (8 leads)
  unsigned* gabort = gs + 1984;              // global abort flag (shared)

  {  // stage W fragments once (reused 512 steps)
    const uint4* src = (const uint4*)(Whf + (size_t)wcg * (2 * 36 * 64 * 8));
    uint4* dst = (uint4*)Wl;
    for (int i = tid; i < 2 * 36 * 64 * 8 / 8; i += 512) dst[i] = src[i];
  }
  {  // stage Wc (9x1024 fp32) once
    const float4* src = (const float4*)Wc;
    float4* dst = (float4*)&Wc_s[0][0];
    for (int i = tid; i < 9 * 1024 / 4; i += 512) dst[i] = src[i];
  }
  if (tid == 0) sAbort = 0;
  if (tid < 9) bco_s[tid] = bcombo[tid];
  if (tid < 32) {
    int g = (tid >> 3) * 1024 + wcg * 8 + (tid & 7);   // c=(q<<3)|jj -> gate col
    bias_s[0][tid] = b0[g];
    bias_s[1][tid] = bcf[g];
  }
  float cs0 = 0.f, cs1 = 0.f;   // cell states: (tid>>3, tid&7), (64+(tid>>3), tid&7)
  __syncthreads();

  const _Float16* ha = hA;   // hx(t-1), zeroed by memset
  _Float16* hn = hB;

  const int bA0 = B0 + mp * 32 + (lane & 15);  // A row, M-tile 0 of pair
  const int bA1 = bA0 + 16;                    // A row, M-tile 1 of pair
  const int ko = (lane >> 4) * 8;              // A k offset within 32-chunk
  const int chb = lane >> 4;                   // chunk sub-offset (ko/8)
  const _Float16* wlb = Wl + (size_t)lane * 8 + (size_t)(kh * 18) * 512;
  unsigned myLead = 0;

  for (int t = 0; t < TT; ++t) {
    // ---- A-fragment prefetch: 36 loads issued, pinned live via asm ----
    // hx cell for h-col group K..K+7 (K = kcg*32-128+ko): chunk = 4*kcg-16+chb
    const _Float16* hb0 = ha + (size_t)chb * CH + (size_t)bA0 * 8;
    const _Float16* hb1 = ha + (size_t)chb * CH + (size_t)bA1 * 8;
    half8 a0[18], a1[18];
    if (kh == 0) {
      const float* x0 = x + ((size_t)bA0 * TT + t) * TIN;
      const float* x1 = x + ((size_t)bA1 * TT + t) * TIN;
      float4 xv0[8], xv1[8];
#pragma unroll
      for (int i = 0; i < 4; ++i) {
        xv0[2 * i]     = *(const float4*)(x0 + i * 32 + ko);
        xv0[2 * i + 1] = *(const float4*)(x0 + i * 32 + ko + 4);
        xv1[2 * i]     = *(const float4*)(x1 + i * 32 + ko);
        xv1[2 * i + 1] = *(const float4*)(x1 + i * 32 + ko + 4);
      }
#pragma unroll
      for (int lc = 4; lc < 18; ++lc) {         // chunks 4*lc-16+chb
        a0[lc] = *(const half8*)(hb0 + (size_t)(4 * lc - 16) * CH);
        a1[lc] = *(const half8*)(hb1 + (size_t)(4 * lc - 16) * CH);
      }
#pragma unroll
      for (int i = 0; i < 4; ++i) {
        half8 v0, v1;
        v0[0] = (_Float16)xv0[2 * i].x; v0[1] = (_Float16)xv0[2 * i].y;
        v0[2] = (_Float16)xv0[2 * i].z; v0[3] = (_Float16)xv0[2 * i].w;
        v0[4] = (_Float16)xv0[2 * i + 1].x; v0[5] = (_Float16)xv0[2 * i + 1].y;
        v0[6] = (_Float16)xv0[2 * i + 1].z; v0[7] = (_Float16)xv0[2 * i + 1].w;
        v1[0] = (_Float16)xv1[2 * i].x; v1[1] = (_Float16)xv1[2 * i].y;
        v1[2] = (_Float16)xv1[2 * i].z; v1[3] = (_Float16)xv1[2 * i].w;
        v1[4] = (_Float16)xv1[2 * i + 1].x; v1[5] = (_Float16)xv1[2 * i + 1].y;
        v1[6] = (_Float16)xv1[2 * i + 1].z; v1[7] = (_Float16)xv1[2 * i + 1].w;
        a0[i] = v0; a1[i] = v1;
      }
    } else {
#pragma unroll
      for (int lc = 0; lc < 18; ++lc) {         // chunks 4*lc+56+chb
        a0[lc] = *(const half8*)(hb0 + (size_t)(4 * lc + 56) * CH);
        a1[lc] = *(const half8*)(hb1 + (size_t)(4 * lc + 56) * CH);
      }
    }
    KEEP18(a0);          // data dep: all a0 values must be in registers here
    KEEP18(a1);          // same for a1 -> loads can't sink into MFMA loop
    __builtin_amdgcn_sched_barrier(0);

    // ---- MFMA loop: 2 LDS reads feed 4 MFMAs (2M x 2N) ----
    f32x4 acc00 = {0.f, 0.f, 0.f, 0.f};
    f32x4 acc01 = {0.f, 0.f, 0.f, 0.f};
    f32x4 acc10 = {0.f, 0.f, 0.f, 0.f};
    f32x4 acc11 = {0.f, 0.f, 0.f, 0.f};
#pragma unroll
    for (int lc = 0; lc < 18; ++lc) {
      half8 bf0 = *(const half8*)(wlb + (size_t)lc * 512);
      half8 bf1 = *(const half8*)(wlb + (size_t)(36 + lc) * 512);
      acc00 = __builtin_amdgcn_mfma_f32_16x16x32_f16(a0[lc], bf0, acc00, 0, 0, 0);
      acc01 = __builtin_amdgcn_mfma_f32_16x16x32_f16(a0[lc], bf1, acc01, 0, 0, 0);
      acc10 = __builtin_amdgcn_mfma_f32_16x16x32_f16(a1[lc], bf0, acc10, 0, 0, 0);
      acc11 = __builtin_amdgcn_mfma_f32_16x16x32_f16(a1[lc], bf1, acc11, 0, 0, 0);
    }
    {  // D layout: col = lane&15, row = (lane>>4)*4 + r
      int rb0 = mp * 32 + (lane >> 4) * 4;
      int rb1 = rb0 + 16;
      int cc = lane & 15;
#pragma unroll
      for (int r = 0; r < 4; ++r) {
        gbuf[kh][rb0 + r][cc] = acc00[r];
        gbuf[kh][rb0 + r][16 + cc] = acc01[r];
        gbuf[kh][rb1 + r][cc] = acc10[r];
        gbuf[kh][rb1 + r][16 + cc] = acc11[r];
      }
    }
    __syncthreads();

    // ---- LSTM finish: 512 threads x 2 gate-sets; cs in registers ----
    {
      const int fb = tid >> 3, fj = tid & 7;   // set A: batch fb; set B: fb+64
      const float* bs = bias_s[(t > 0) ? 1 : 0];
      float vi = gbuf[0][fb][fj]      + gbuf[1][fb][fj]      + bs[fj];
      float vf = gbuf[0][fb][8 + fj]  + gbuf[1][fb][8 + fj]  + bs[8 + fj];
      float vg = gbuf[0][fb][16 + fj] + gbuf[1][fb][16 + fj] + bs[16 + fj];
      float vo = gbuf[0][fb][24 + fj] + gbuf[1][fb][24 + fj] + bs[24 + fj];
      float ig = sigm(vi), fg = sigm(vf), gg = tanh_f(vg), og = sigm(vo);
      float cn = fg * cs0 + ig * gg;
      cs0 = cn;
      htmp[fb][fj] = (_Float16)(og * tanh_f(cn));

      const int fb2 = fb + 64;
      float vi2 = gbuf[0][fb2][fj]      + gbuf[1][fb2][fj]      + bs[fj];
      float vf2 = gbuf[0][fb2][8 + fj]  + gbuf[1][fb2][8 + fj]  + bs[8 + fj];
      float vg2 = gbuf[0][fb2][16 + fj] + gbuf[1][fb2][16 + fj] + bs[16 + fj];
      float vo2 = gbuf[0][fb2][24 + fj] + gbuf[1][fb2][24 + fj] + bs[24 + fj];
      float ig2 = sigm(vi2), fg2 = sigm(vf2), gg2 = tanh_f(vg2), og2 = sigm(vo2);
      float cn2 = fg2 * cs1 + ig2 * gg2;
      cs1 = cn2;
      htmp[fb2][fj] = (_Float16)(og2 * tanh_f(cn2));
    }
    __syncthreads();

    // ---- h store: CONTIGUOUS 2KB block hx[wcg][B0+tid][*] (full lines) ----
    if (tid < 128) {
      uint4 hv = *(const uint4*)&htmp[tid][0];
      st_h16_agent(hn + (size_t)wcg * CH + (size_t)(B0 + tid) * 8, hv);
    }
    __threadfence_block();   // drain own vmcnt: stores visible at LLC
    __syncthreads();         // whole block drained

    // ---- barrier arrival; leads bump root ----
    if (tid == 0) {
      unsigned old = __hip_atomic_fetch_add(gcnt_grp, 1u, __ATOMIC_RELAXED, __HIP_MEMORY_SCOPE_AGENT);
      myLead = (old == (unsigned)(t + 1) * 16u - 1u);
      if (myLead)
        __hip_atomic_fetch_add(gcnt_root, 1u, __ATOMIC_RELAXED, __HIP_MEMORY_SCOPE_AGENT);
    }

    // ---- out(t-1): wave wv -> col wv (wave 0 also col 8), one batch ----
    if (t > 0) {
      const _Float16* hxb = ha + (size_t)myb * 8;
#pragma unroll
      for (int p = 0; p < 2; ++p) {
        int ch = 2 * lane + p;
        half8 hv = *(const half8*)(hxb + (size_t)ch * CH);
        const float* wr = &Wc_s[wv][ch * 8];
        float s = 0.f;
#pragma unroll
        for (int j = 0; j < 8; ++j) s += (float)hv[j] * wr[j];
        if (p == 0) {
#pragma unroll
          for (int off = 32; off > 0; off >>= 1) s += __shfl_down(s, off, 64);
          if (lane == 0) dout[((size_t)myb * TT + (t - 1)) * TOUT + wv] = s + bco_s[wv];
        } else {
          // accumulate second chunk into a second pass reduction
          float s2 = s;
#pragma unroll
          for (int off = 32; off > 0; off >>= 1) s2 += __shfl_down(s2, off, 64);
          if (lane == 0) dout[((size_t)myb * TT + (t - 1)) * TOUT + wv] += s2;
        }
      }
      if (wv == 0) {
        const float* wr8 = &Wc_s[8][0];
        float s = 0.f;
#pragma unroll
        for (int p = 0; p < 2; ++p) {
          int ch = 2 * lane + p;
          half8 hv = *(const half8*)(hxb + (size_t)ch * CH);
#pragma unroll
          for (int j = 0; j < 8; ++j) s += (float)hv[j] * wr8[ch * 8 + j];
        }
#pragma unroll
        for (int off = 32; off > 0; off >>= 1) s += __shfl_down(s, off, 64);
        if (lane == 0) dout[((size_t)myb * TT + (t - 1)) * TOUT + 8] = s + bco_s[8];
      }
    }

    // ---- barrier: ALL tid0s poll root directly (bounded; abort) + inv ----
    if (tid == 0) {
      bool ab = false;
      unsigned guard = 0;
      const unsigned tgt = (unsigned)(t + 1) * 8u;
      while (__hip_atomic_load(gcnt_root, __ATOMIC_RELAXED, __HIP_MEMORY_SCOPE_AGENT) < tgt) {
        __builtin_amdgcn_s_sleep(1);
        if (((++guard) & 255u) == 0u &&
            __hip_atomic_load(gabort, __ATOMIC_RELAXED, __HIP_MEMORY_SCOPE_AGENT) != 0u) { ab = true; break; }
        if (guard > 200000u) {
          __hip_atomic_store(gabort, 1u, __ATOMIC_RELAXED, __HIP_MEMORY_SCOPE_AGENT);
          ab = true; break;
        }
      }
      if (ab) {
        sAbort = 1;
      } else {
        // ACQUIRE load: emits buffer_inv (invalidate stale L1/L2), no wbl2.
        (void)__hip_atomic_load(gcnt_root, __ATOMIC_ACQUIRE, __HIP_MEMORY_SCOPE_AGENT);
      }
    }
    __syncthreads();
    if (sAbort) return;   // wrong answer beats a wedged GPU

    const _Float16* tp = ha; ha = hn; hn = (_Float16*)tp;
  }

  // ---- epilogue: out(TT-1) for this block's batch from final h ----
  {
    const _Float16* hxb = ha + (size_t)myb * 8;
    {
      float s = 0.f;
#pragma unroll
      for (int p = 0; p < 2; ++p) {
        int ch = 2 * lane + p;
        half8 hv = *(const half8*)(hxb + (size_t)ch * CH);
        const float* wr = &Wc_s[wv][ch * 8];
#pragma unroll
        for (int j = 0; j < 8; ++j) s += (float)hv[j] * wr[j];
      }
#pragma unroll
      for (int off = 32; off > 0; off >>= 1) s += __shfl_down(s, off, 64);
      if (lane == 0) dout[((size_t)myb * TT + (TT - 1)) * TOUT + wv] = s + bco_s[wv];
    }
    if (wv == 0) {
      const float* wr8 = &Wc_s[8][0];
      float s = 0.f;
#pragma unroll
      for (int p = 0; p < 2; ++p) {
        int ch = 2 * lane + p;
        half8 hv = *(const half8*)(hxb + (size_t)ch * CH);
#pragma unroll
        for (int j = 0; j < 8; ++j) s += (float)hv[j] * wr8[ch * 8 + j];
      }
#pragma unroll
      for (int off = 32; off > 0; off >>= 1) s += __shfl_down(s, off, 64);
      if (lane == 0) dout[((size_t)myb * TT + (TT - 1)) * TOUT + 8] = s + bco_s[8];
    }
  }
}

// ---------------- launch ----------------

extern "C" void kernel_launch(void* const* d_in, const int* in_sizes, int n_in,
                              void* d_out, int out_size, void* d_ws, size_t ws_size,
                              hipStream_t stream) {
  if (ws_size < OB_END) return;   // clean fail, no OOB

  const float* x     = (const float*)d_in[0];
  const float* W_ih  = (const float*)d_in[1];
  const float* b_ih  = (const float*)d_in[2];
  const float* W_hh  = (const float*)d_in[3];
  const float* b_hh  = (const float*)d_in[4];
  const float* W_h2h = (const float*)d_in[5];
  const float* b_h2h = (const float*)d_in[6];
  const float* W_h2o = (const float*)d_in[7];
  const float* b_h2o = (const float*)d_in[8];
  const int*   lens  = (const int*)d_in[9];

  char* ws = (char*)d_ws;
  float* dout    = (float*)d_out;
  _Float16* Whf  = (_Float16*)(ws + OB_WHF);
  float* Wcombo  = (float*)(ws + OB_WCB);
  float* bcombo  = (float*)(ws + OB_BCB);
  float* b0      = (float*)(ws + OB_B0);
  float* bconst  = (float*)(ws + OB_BC);
  _Float16* h0   = (_Float16*)(ws + OB_H0);
  _Float16* h1   = (_Float16*)(ws + OB_H1);
  unsigned* gs   = (unsigned*)(ws + OB_GC);

  // zero hx ping-pong + barrier counters every call (graph-replay safe)
  hipMemsetAsync((void*)(ws + OB_H0), 0, OB_END - OB_H0, stream);

  k_combo<<<36, 256, 0, stream>>>(W_h2o, W_h2h, b_h2h, b_h2o, Wcombo, bcombo);
  k_wblk<<<1024, 256, 0, stream>>>(W_hh, W_ih, W_h2o, W_h2h, Whf);
  k_bias<<<16, 256, 0, stream>>>(b_ih, b_hh, W_hh, W_ih, b_h2h, bcombo, b0, bconst);
  k_fillx<<<2048, 256, 0, stream>>>(W_ih, Whf);
  k_len<<<1, 256, 0, stream>>>(lens, dout);

  k_main<<<256, 512, 0, stream>>>(x, Whf, Wcombo, b0, bconst, bcombo, h0, h1, gs, dout);
}

// Round 13
// 5048.860 us; speedup vs baseline: 1.4912x; 1.0814x over previous
//
#include <hip/hip_runtime.h>
#include <math.h>

#define TB 256      // batch
#define TT 512      // timesteps
#define TIN 128     // input size
#define TH 1024     // hidden
#define TOUT 9      // output coords
#define KD 1152     // TIN + TH

typedef _Float16 half8 __attribute__((ext_vector_type(8)));
typedef float f32x4 __attribute__((ext_vector_type(4)));

// ---- workspace layout (BYTE offsets) ----
#define OB_WHF   0ull
#define SB_WHF   (128ull*2*36*64*8*2)   // 9,437,184 B  f16 B-fragments [wcg][nt][kc][l][j]
#define OB_WCB   (OB_WHF + SB_WHF)      // Wcombo fp32 [9][1024]
#define SB_WCB   (9ull*1024*4)
#define OB_BCB   (OB_WCB + SB_WCB)      // bcombo fp32 [9] (pad 16)
#define SB_BCB   64ull
#define OB_B0    (OB_BCB + SB_BCB)      // bias t==0 [4096] fp32
#define SB_B0    (4096ull*4)
#define OB_BC    (OB_B0 + SB_B0)        // bias t>0  [4096] fp32
#define SB_BC    (4096ull*4)
#define OB_H0    (OB_BC + SB_BC)        // hx ping [128 chunk][256 b][8] f16 (chunk-major)
#define SB_H     (256ull*1024*2)
#define OB_H1    (OB_H0 + SB_H)         // hx pong
#define OB_GC    (OB_H1 + SB_H)         // barrier counters (two halves, 128B lines)
#define OB_END   (OB_GC + 8192ull)      // ~10.5 MB total

// fragment address for gate col `col` (0..4095), k (0..1151)
__device__ __forceinline__ size_t frag_addr(int col, int k) {
  int q = col >> 10, hcol = col & 1023;
  int wcg = hcol >> 3, jj = hcol & 7;
  int c = (q << 3) | jj;
  int nt = c >> 4, n = c & 15;
  int kc = k >> 5, ls = (k >> 3) & 3, je = k & 7;
  return ((((size_t)wcg * 2 + nt) * 36 + kc) * 64 + ((ls << 4) | n)) * 8 + je;
}

// ---- agent-scope (LLC write-through) 2B h store ----
__device__ __forceinline__ void st_h2_agent(_Float16* p, _Float16 v) {
  union { _Float16 h; unsigned short u; } c; c.h = v;
  __hip_atomic_store((unsigned short*)p, c.u, __ATOMIC_RELAXED, __HIP_MEMORY_SCOPE_AGENT);
}

// ---------------- prep kernels (unchanged, verified rounds 5-12) ----------------

__global__ __launch_bounds__(256) void k_combo(const float* __restrict__ W_h2o,
                                               const float* __restrict__ W_h2h,
                                               const float* __restrict__ b_h2h,
                                               const float* __restrict__ b_h2o,
                                               float* __restrict__ Wcombo,
                                               float* __restrict__ bcombo) {
  int gid = blockIdx.x * 256 + threadIdx.x;
  if (gid < 9 * 1024) {
    int r = gid >> 10, m = gid & 1023;
    float s = 0.f;
    for (int j = 0; j < 1024; ++j) s += W_h2o[r * 1024 + j] * W_h2h[j * 1024 + m];
    Wcombo[gid] = s;
  }
  if (gid < 9) {
    float s = b_h2o[gid];
    for (int j = 0; j < 1024; ++j) s += W_h2o[gid * 1024 + j] * b_h2h[j];
    bcombo[gid] = s;
  }
}

__global__ __launch_bounds__(256) void k_wblk(const float* __restrict__ W_hh,
                                              const float* __restrict__ W_ih,
                                              const float* __restrict__ W_h2o,
                                              const float* __restrict__ W_h2h,
                                              _Float16* __restrict__ Whf) {
  __shared__ float As2[16][68];
  __shared__ float Bs[16][68];
  __shared__ float Wio_s[64][12];
  __shared__ float Bo[9][16];
  const int tid = threadIdx.x;
  const int bm = (blockIdx.x & 15) * 64;   // m tile
  const int bc = (blockIdx.x >> 4) * 64;   // col tile
  const int tx = tid & 15, ty = tid >> 4;
  const int cl = tid >> 2, kq4 = tid & 3;

  for (int i = tid; i < 64 * 9; i += 256) {
    int row = i / 9, r = i % 9;
    Wio_s[row][r] = W_ih[(size_t)(bc + row) * 137 + 128 + r];
  }

  float acc[4][4];
#pragma unroll
  for (int i = 0; i < 4; ++i)
#pragma unroll
    for (int j = 0; j < 4; ++j) acc[i][j] = 0.f;

  for (int k0 = 0; k0 < 1024; k0 += 16) {
    __syncthreads();
    if (tid < 144) { int r = tid >> 4, kk = tid & 15; Bo[r][kk] = W_h2o[(size_t)r * 1024 + k0 + kk]; }
    { int kk = tid >> 4, q = tid & 15;
      float4 v = *(const float4*)(W_h2h + (size_t)(k0 + kk) * 1024 + bm + q * 4);
      *(float4*)&Bs[kk][q * 4] = v; }
    float4 av = *(const float4*)(W_hh + (size_t)(bc + cl) * 1024 + k0 + kq4 * 4);
    __syncthreads();
    {
      float c0 = 0.f, c1 = 0.f, c2 = 0.f, c3 = 0.f;
#pragma unroll
      for (int r = 0; r < 9; ++r) {
        float wio = Wio_s[cl][r];
        c0 += wio * Bo[r][kq4 * 4 + 0];
        c1 += wio * Bo[r][kq4 * 4 + 1];
        c2 += wio * Bo[r][kq4 * 4 + 2];
        c3 += wio * Bo[r][kq4 * 4 + 3];
      }
      As2[kq4 * 4 + 0][cl] = av.x + c0;
      As2[kq4 * 4 + 1][cl] = av.y + c1;
      As2[kq4 * 4 + 2][cl] = av.z + c2;
      As2[kq4 * 4 + 3][cl] = av.w + c3;
    }
    __syncthreads();
#pragma unroll
    for (int kk = 0; kk < 16; ++kk) {
      float4 a = *(const float4*)&As2[kk][ty * 4];
      float4 bv = *(const float4*)&Bs[kk][tx * 4];
      acc[0][0] += a.x * bv.x; acc[0][1] += a.x * bv.y; acc[0][2] += a.x * bv.z; acc[0][3] += a.x * bv.w;
      acc[1][0] += a.y * bv.x; acc[1][1] += a.y * bv.y; acc[1][2] += a.y * bv.z; acc[1][3] += a.y * bv.w;
      acc[2][0] += a.z * bv.x; acc[2][1] += a.z * bv.y; acc[2][2] += a.z * bv.z; acc[2][3] += a.z * bv.w;
      acc[3][0] += a.w * bv.x; acc[3][1] += a.w * bv.y; acc[3][2] += a.w * bv.z; acc[3][3] += a.w * bv.w;
    }
  }
#pragma unroll
  for (int i = 0; i < 4; ++i)
#pragma unroll
    for (int j = 0; j < 4; ++j) {
      int col = bc + ty * 4 + i;          // gate col
      int m = bm + tx * 4 + j;            // h index -> k = 128+m
      Whf[frag_addr(col, 128 + m)] = (_Float16)acc[i][j];
    }
}

__global__ __launch_bounds__(256) void k_bias(const float* __restrict__ b_ih,
                                              const float* __restrict__ b_hh,
                                              const float* __restrict__ W_hh,
                                              const float* __restrict__ W_ih,
                                              const float* __restrict__ b_h2h,
                                              const float* __restrict__ bcombo,
                                              float* __restrict__ b0,
                                              float* __restrict__ bconst) {
  int col = blockIdx.x * 256 + threadIdx.x;
  float base = b_ih[col] + b_hh[col];
  b0[col] = base;
  float s = 0.f;
  for (int j = 0; j < 1024; ++j) s += W_hh[(size_t)col * 1024 + j] * b_h2h[j];
#pragma unroll
  for (int r = 0; r < 9; ++r) s += W_ih[(size_t)col * 137 + 128 + r] * bcombo[r];
  bconst[col] = base + s;
}

__global__ __launch_bounds__(256) void k_fillx(const float* __restrict__ W_ih,
                                               _Float16* __restrict__ Whf) {
  int gid = blockIdx.x * 256 + threadIdx.x;   // 4096*128
  int col = gid >> 7, k = gid & 127;
  Whf[frag_addr(col, k)] = (_Float16)W_ih[(size_t)col * 137 + k];
}

__global__ void k_len(const int* __restrict__ len, float* __restrict__ dout) {
  int i = threadIdx.x;
  if (i < TB) dout[(size_t)TB * TT * TOUT + i] = (float)len[i];
}

// ---------------- persistent main kernel ----------------
// r12 structure (chunk-major hx, split per-half tree barrier, write-through
// stores + cached reads + invalidate-only ACQUIRE) with the barrier-wait
// window filled: gates(t+1)'s x-part (loads+cvt+16 MFMAs, kh==0 waves) runs
// between arrival and poll, accumulating into persistent acc registers that
// the post-barrier h-part extends. Finish writes h via direct coalesced 2B
// agent stores (htmp + one syncthreads removed).

__device__ __forceinline__ float sigm(float v) { return 1.f / (1.f + __expf(-v)); }
__device__ __forceinline__ float tanh_f(float v) {
  float e2 = __expf(2.f * v);
  return (e2 - 1.f) / (e2 + 1.f);
}

#define KEEP14(a) asm volatile("" :: "v"(a[0]), "v"(a[1]), "v"(a[2]), "v"(a[3]), \
  "v"(a[4]), "v"(a[5]), "v"(a[6]), "v"(a[7]), "v"(a[8]), "v"(a[9]), "v"(a[10]), \
  "v"(a[11]), "v"(a[12]), "v"(a[13]))
#define KEEP18(a) asm volatile("" :: "v"(a[0]), "v"(a[1]), "v"(a[2]), "v"(a[3]), \
  "v"(a[4]), "v"(a[5]), "v"(a[6]), "v"(a[7]), "v"(a[8]), "v"(a[9]), "v"(a[10]), \
  "v"(a[11]), "v"(a[12]), "v"(a[13]), "v"(a[14]), "v"(a[15]), "v"(a[16]), "v"(a[17]))

__global__ __launch_bounds__(512, 2) void k_main(const float* __restrict__ x,
                                                 const _Float16* __restrict__ Whf,
                                                 const float* __restrict__ Wc,
                                                 const float* __restrict__ b0,
                                                 const float* __restrict__ bcf,
                                                 const float* __restrict__ bcombo,
                                                 _Float16* __restrict__ hA,
                                                 _Float16* __restrict__ hB,
                                                 unsigned* __restrict__ gs,
                                                 float* __restrict__ dout) {
  __shared__ _Float16 Wl[2 * 36 * 64 * 8];   // 73,728 B
  __shared__ float gbuf[2][128][36];         // 36,864 B (K-half partials)
  __shared__ float Wc_s[9][1024];            // 36,864 B out weights
  __shared__ float bias_s[2][32];
  __shared__ float bco_s[12];
  __shared__ int sAbort;

  const int bx = blockIdx.x;
  const int half_id = bx >> 7;       // 0/1: independent batch-half
  const int wcg = bx & 127;          // col-group: h-cols 8*wcg..+7 = chunk wcg
  const int B0 = half_id * 128;      // batch base
  const int myb = B0 + wcg;          // this block's out-GEMV batch
  const int grp = wcg >> 4;          // barrier group within half (8 groups x 16)
  const int tid = threadIdx.x;
  const int lane = tid & 63;
  const int wv = tid >> 6;           // 0..7
  const int mp = wv & 3, kh = wv >> 2;

  const size_t CH = (size_t)TB * 8;  // halfwords per chunk (256 batches x 8)

  unsigned* hbase = gs + half_id * 1024;     // per-half barrier region
  unsigned* gcnt_grp = hbase + grp * 32;     // arrival counter (own 128B line)
  unsigned* gcnt_root = hbase + 8 * 32;      // root counter (8 leads)
  unsigned* gabort = gs + 1984;              // global abort flag (shared)

  {  // stage W fragments once (reused 512 steps)
    const uint4* src = (const uint4*)(Whf + (size_t)wcg * (2 * 36 * 64 * 8));
    uint4* dst = (uint4*)Wl;
    for (int i = tid; i < 2 * 36 * 64 * 8 / 8; i += 512) dst[i] = src[i];
  }
  {  // stage Wc (9x1024 fp32) once
    const float4* src = (const float4*)Wc;
    float4* dst = (float4*)&Wc_s[0][0];
    for (int i = tid; i < 9 * 1024 / 4; i += 512) dst[i] = src[i];
  }
  if (tid == 0) sAbort = 0;
  if (tid < 9) bco_s[tid] = bcombo[tid];
  if (tid < 32) {
    int g = (tid >> 3) * 1024 + wcg * 8 + (tid & 7);   // c=(q<<3)|jj -> gate col
    bias_s[0][tid] = b0[g];
    bias_s[1][tid] = bcf[g];
  }
  float cs0 = 0.f, cs1 = 0.f;   // cell states: (tid>>3, tid&7), (64+(tid>>3), tid&7)
  __syncthreads();

  const _Float16* ha = hA;   // hx(t-1), zeroed by memset
  _Float16* hn = hB;

  const int bA0 = B0 + mp * 32 + (lane & 15);  // A row, M-tile 0 of pair
  const int bA1 = bA0 + 16;                    // A row, M-tile 1 of pair
  const int ko = (lane >> 4) * 8;              // A k offset within 32-chunk
  const int chb = lane >> 4;                   // chunk sub-offset (ko/8)
  const _Float16* wlb = Wl + (size_t)lane * 8 + (size_t)(kh * 18) * 512;
  unsigned myLead = 0;

  // persistent accumulators: x-part(t) computed during t-1's barrier wait
  f32x4 acc00 = {0.f, 0.f, 0.f, 0.f};
  f32x4 acc01 = {0.f, 0.f, 0.f, 0.f};
  f32x4 acc10 = {0.f, 0.f, 0.f, 0.f};
  f32x4 acc11 = {0.f, 0.f, 0.f, 0.f};

  // x-part MFMA for timestep tt (kh==0 waves only) — accumulates into acc*
#define XPART(tt) do { \
    const float* x0_ = x + ((size_t)bA0 * TT + (tt)) * TIN; \
    const float* x1_ = x + ((size_t)bA1 * TT + (tt)) * TIN; \
    _Pragma("unroll") \
    for (int i_ = 0; i_ < 4; ++i_) { \
      float4 p0 = *(const float4*)(x0_ + i_ * 32 + ko); \
      float4 p1 = *(const float4*)(x0_ + i_ * 32 + ko + 4); \
      float4 q0 = *(const float4*)(x1_ + i_ * 32 + ko); \
      float4 q1 = *(const float4*)(x1_ + i_ * 32 + ko + 4); \
      half8 v0_, v1_; \
      v0_[0] = (_Float16)p0.x; v0_[1] = (_Float16)p0.y; v0_[2] = (_Float16)p0.z; v0_[3] = (_Float16)p0.w; \
      v0_[4] = (_Float16)p1.x; v0_[5] = (_Float16)p1.y; v0_[6] = (_Float16)p1.z; v0_[7] = (_Float16)p1.w; \
      v1_[0] = (_Float16)q0.x; v1_[1] = (_Float16)q0.y; v1_[2] = (_Float16)q0.z; v1_[3] = (_Float16)q0.w; \
      v1_[4] = (_Float16)q1.x; v1_[5] = (_Float16)q1.y; v1_[6] = (_Float16)q1.z; v1_[7] = (_Float16)q1.w; \
      half8 bf0_ = *(const half8*)(wlb + (size_t)i_ * 512); \
      half8 bf1_ = *(const half8*)(wlb + (size_t)(36 + i_) * 512); \
      acc00 = __builtin_amdgcn_mfma_f32_16x16x32_f16(v0_, bf0_, acc00, 0, 0, 0); \
      acc01 = __builtin_amdgcn_mfma_f32_16x16x32_f16(v0_, bf1_, acc01, 0, 0, 0); \
      acc10 = __builtin_amdgcn_mfma_f32_16x16x32_f16(v1_, bf0_, acc10, 0, 0, 0); \
      acc11 = __builtin_amdgcn_mfma_f32_16x16x32_f16(v1_, bf1_, acc11, 0, 0, 0); \
    } \
  } while (0)

  if (kh == 0) XPART(0);   // t=0's x-part (h(-1)=0, so h-part of t=0 adds zeros)

  for (int t = 0; t < TT; ++t) {
    // ---- h-fragment prefetch (post-inv), pinned live via asm ----
    const _Float16* hb0 = ha + (size_t)chb * CH + (size_t)bA0 * 8;
    const _Float16* hb1 = ha + (size_t)chb * CH + (size_t)bA1 * 8;
    if (kh == 0) {
      half8 a0[14], a1[14];
#pragma unroll
      for (int i = 0; i < 14; ++i) {            // lc = 4+i, chunk 4*lc-16+chb
        a0[i] = *(const half8*)(hb0 + (size_t)(4 * (4 + i) - 16) * CH);
        a1[i] = *(const half8*)(hb1 + (size_t)(4 * (4 + i) - 16) * CH);
      }
      KEEP14(a0); KEEP14(a1);
      __builtin_amdgcn_sched_barrier(0);
#pragma unroll
      for (int i = 0; i < 14; ++i) {
        const int lc = 4 + i;
        half8 bf0 = *(const half8*)(wlb + (size_t)lc * 512);
        half8 bf1 = *(const half8*)(wlb + (size_t)(36 + lc) * 512);
        acc00 = __builtin_amdgcn_mfma_f32_16x16x32_f16(a0[i], bf0, acc00, 0, 0, 0);
        acc01 = __builtin_amdgcn_mfma_f32_16x16x32_f16(a0[i], bf1, acc01, 0, 0, 0);
        acc10 = __builtin_amdgcn_mfma_f32_16x16x32_f16(a1[i], bf0, acc10, 0, 0, 0);
        acc11 = __builtin_amdgcn_mfma_f32_16x16x32_f16(a1[i], bf1, acc11, 0, 0, 0);
      }
    } else {
      half8 a0[18], a1[18];
#pragma unroll
      for (int i = 0; i < 18; ++i) {            // chunk 4*i+56+chb
        a0[i] = *(const half8*)(hb0 + (size_t)(4 * i + 56) * CH);
        a1[i] = *(const half8*)(hb1 + (size_t)(4 * i + 56) * CH);
      }
      KEEP18(a0); KEEP18(a1);
      __builtin_amdgcn_sched_barrier(0);
#pragma unroll
      for (int i = 0; i < 18; ++i) {
        half8 bf0 = *(const half8*)(wlb + (size_t)i * 512);
        half8 bf1 = *(const half8*)(wlb + (size_t)(36 + i) * 512);
        acc00 = __builtin_amdgcn_mfma_f32_16x16x32_f16(a0[i], bf0, acc00, 0, 0, 0);
        acc01 = __builtin_amdgcn_mfma_f32_16x16x32_f16(a0[i], bf1, acc01, 0, 0, 0);
        acc10 = __builtin_amdgcn_mfma_f32_16x16x32_f16(a1[i], bf0, acc10, 0, 0, 0);
        acc11 = __builtin_amdgcn_mfma_f32_16x16x32_f16(a1[i], bf1, acc11, 0, 0, 0);
      }
    }
    {  // D layout: col = lane&15, row = (lane>>4)*4 + r
      int rb0 = mp * 32 + (lane >> 4) * 4;
      int rb1 = rb0 + 16;
      int cc = lane & 15;
#pragma unroll
      for (int r = 0; r < 4; ++r) {
        gbuf[kh][rb0 + r][cc] = acc00[r];
        gbuf[kh][rb0 + r][16 + cc] = acc01[r];
        gbuf[kh][rb1 + r][cc] = acc10[r];
        gbuf[kh][rb1 + r][16 + cc] = acc11[r];
      }
    }
    __syncthreads();

    // ---- LSTM finish: direct coalesced 2B agent stores (no htmp) ----
    {
      const int fb = tid >> 3, fj = tid & 7;   // set A: batch fb; set B: fb+64
      const float* bs = bias_s[(t > 0) ? 1 : 0];
      float vi = gbuf[0][fb][fj]      + gbuf[1][fb][fj]      + bs[fj];
      float vf = gbuf[0][fb][8 + fj]  + gbuf[1][fb][8 + fj]  + bs[8 + fj];
      float vg = gbuf[0][fb][16 + fj] + gbuf[1][fb][16 + fj] + bs[16 + fj];
      float vo = gbuf[0][fb][24 + fj] + gbuf[1][fb][24 + fj] + bs[24 + fj];
      float ig = sigm(vi), fg = sigm(vf), gg = tanh_f(vg), og = sigm(vo);
      float cn = fg * cs0 + ig * gg;
      cs0 = cn;
      st_h2_agent(hn + (size_t)wcg * CH + (size_t)(B0 + fb) * 8 + fj,
                  (_Float16)(og * tanh_f(cn)));

      const int fb2 = fb + 64;
      float vi2 = gbuf[0][fb2][fj]      + gbuf[1][fb2][fj]      + bs[fj];
      float vf2 = gbuf[0][fb2][8 + fj]  + gbuf[1][fb2][8 + fj]  + bs[8 + fj];
      float vg2 = gbuf[0][fb2][16 + fj] + gbuf[1][fb2][16 + fj] + bs[16 + fj];
      float vo2 = gbuf[0][fb2][24 + fj] + gbuf[1][fb2][24 + fj] + bs[24 + fj];
      float ig2 = sigm(vi2), fg2 = sigm(vf2), gg2 = tanh_f(vg2), og2 = sigm(vo2);
      float cn2 = fg2 * cs1 + ig2 * gg2;
      cs1 = cn2;
      st_h2_agent(hn + (size_t)wcg * CH + (size_t)(B0 + fb2) * 8 + fj,
                  (_Float16)(og2 * tanh_f(cn2)));
    }
    __threadfence_block();   // drain own vmcnt: stores visible at LLC
    __syncthreads();         // whole block drained

    // ---- barrier arrival; leads bump root ----
    if (tid == 0) {
      unsigned old = __hip_atomic_fetch_add(gcnt_grp, 1u, __ATOMIC_RELAXED, __HIP_MEMORY_SCOPE_AGENT);
      myLead = (old == (unsigned)(t + 1) * 16u - 1u);
      if (myLead)
        __hip_atomic_fetch_add(gcnt_root, 1u, __ATOMIC_RELAXED, __HIP_MEMORY_SCOPE_AGENT);
    }

    // ---- wait-window work 1: out(t-1) GEMV on ha (pre-inv cached) ----
    if (t > 0) {
      const _Float16* hxb = ha + (size_t)myb * 8;
      {
        float s = 0.f;
#pragma unroll
        for (int p = 0; p < 2; ++p) {
          int ch = 2 * lane + p;
          half8 hv = *(const half8*)(hxb + (size_t)ch * CH);
          const float* wr = &Wc_s[wv][ch * 8];
#pragma unroll
          for (int j = 0; j < 8; ++j) s += (float)hv[j] * wr[j];
        }
#pragma unroll
        for (int off = 32; off > 0; off >>= 1) s += __shfl_down(s, off, 64);
        if (lane == 0) dout[((size_t)myb * TT + (t - 1)) * TOUT + wv] = s + bco_s[wv];
      }
      if (wv == 0) {
        const float* wr8 = &Wc_s[8][0];
        float s = 0.f;
#pragma unroll
        for (int p = 0; p < 2; ++p) {
          int ch = 2 * lane + p;
          half8 hv = *(const half8*)(hxb + (size_t)ch * CH);
#pragma unroll
          for (int j = 0; j < 8; ++j) s += (float)hv[j] * wr8[ch * 8 + j];
        }
#pragma unroll
        for (int off = 32; off > 0; off >>= 1) s += __shfl_down(s, off, 64);
        if (lane == 0) dout[((size_t)myb * TT + (t - 1)) * TOUT + 8] = s + bco_s[8];
      }
    }

    // ---- wait-window work 2: x-part of gates(t+1) into fresh acc ----
    acc00 = (f32x4){0.f, 0.f, 0.f, 0.f};
    acc01 = (f32x4){0.f, 0.f, 0.f, 0.f};
    acc10 = (f32x4){0.f, 0.f, 0.f, 0.f};
    acc11 = (f32x4){0.f, 0.f, 0.f, 0.f};
    if (kh == 0 && t + 1 < TT) XPART(t + 1);

    // ---- barrier: ALL tid0s poll root directly (bounded; abort) + inv ----
    if (tid == 0) {
      bool ab = false;
      unsigned guard = 0;
      const unsigned tgt = (unsigned)(t + 1) * 8u;
      while (__hip_atomic_load(gcnt_root, __ATOMIC_RELAXED, __HIP_MEMORY_SCOPE_AGENT) < tgt) {
        __builtin_amdgcn_s_sleep(1);
        if (((++guard) & 255u) == 0u &&
            __hip_atomic_load(gabort, __ATOMIC_RELAXED, __HIP_MEMORY_SCOPE_AGENT) != 0u) { ab = true; break; }
        if (guard > 200000u) {
          __hip_atomic_store(gabort, 1u, __ATOMIC_RELAXED, __HIP_MEMORY_SCOPE_AGENT);
          ab = true; break;
        }
      }
      if (ab) {
        sAbort = 1;
      } else {
        // ACQUIRE load: emits buffer_inv (invalidate stale L1/L2), no wbl2.
        (void)__hip_atomic_load(gcnt_root, __ATOMIC_ACQUIRE, __HIP_MEMORY_SCOPE_AGENT);
      }
    }
    __syncthreads();
    if (sAbort) return;   // wrong answer beats a wedged GPU

    const _Float16* tp = ha; ha = hn; hn = (_Float16*)tp;
  }

  // ---- epilogue: out(TT-1) for this block's batch from final h ----
  {
    const _Float16* hxb = ha + (size_t)myb * 8;
    {
      float s = 0.f;
#pragma unroll
      for (int p = 0; p < 2; ++p) {
        int ch = 2 * lane + p;
        half8 hv = *(const half8*)(hxb + (size_t)ch * CH);
        const float* wr = &Wc_s[wv][ch * 8];
#pragma unroll
        for (int j = 0; j < 8; ++j) s += (float)hv[j] * wr[j];
      }
#pragma unroll
      for (int off = 32; off > 0; off >>= 1) s += __shfl_down(s, off, 64);
      if (lane == 0) dout[((size_t)myb * TT + (TT - 1)) * TOUT + wv] = s + bco_s[wv];
    }
    if (wv == 0) {
      const float* wr8 = &Wc_s[8][0];
      float s = 0.f;
#pragma unroll
      for (int p = 0; p < 2; ++p) {
        int ch = 2 * lane + p;
        half8 hv = *(const half8*)(hxb + (size_t)ch * CH);
#pragma unroll
        for (int j = 0; j < 8; ++j) s += (float)hv[j] * wr8[ch * 8 + j];
      }
#pragma unroll
      for (int off = 32; off > 0; off >>= 1) s += __shfl_down(s, off, 64);
      if (lane == 0) dout[((size_t)myb * TT + (TT - 1)) * TOUT + 8] = s + bco_s[8];
    }
  }
}

// ---------------- launch ----------------

extern "C" void kernel_launch(void* const* d_in, const int* in_sizes, int n_in,
                              void* d_out, int out_size, void* d_ws, size_t ws_size,
                              hipStream_t stream) {
  if (ws_size < OB_END) return;   // clean fail, no OOB

  const float* x     = (const float*)d_in[0];
  const float* W_ih  = (const float*)d_in[1];
  const float* b_ih  = (const float*)d_in[2];
  const float* W_hh  = (const float*)d_in[3];
  const float* b_hh  = (const float*)d_in[4];
  const float* W_h2h = (const float*)d_in[5];
  const float* b_h2h = (const float*)d_in[6];
  const float* W_h2o = (const float*)d_in[7];
  const float* b_h2o = (const float*)d_in[8];
  const int*   lens  = (const int*)d_in[9];

  char* ws = (char*)d_ws;
  float* dout    = (float*)d_out;
  _Float16* Whf  = (_Float16*)(ws + OB_WHF);
  float* Wcombo  = (float*)(ws + OB_WCB);
  float* bcombo  = (float*)(ws + OB_BCB);
  float* b0      = (float*)(ws + OB_B0);
  float* bconst  = (float*)(ws + OB_BC);
  _Float16* h0   = (_Float16*)(ws + OB_H0);
  _Float16* h1   = (_Float16*)(ws + OB_H1);
  unsigned* gs   = (unsigned*)(ws + OB_GC);

  // zero hx ping-pong + barrier counters every call (graph-replay safe)
  hipMemsetAsync((void*)(ws + OB_H0), 0, OB_END - OB_H0, stream);

  k_combo<<<36, 256, 0, stream>>>(W_h2o, W_h2h, b_h2h, b_h2o, Wcombo, bcombo);
  k_wblk<<<1024, 256, 0, stream>>>(W_hh, W_ih, W_h2o, W_h2h, Whf);
  k_bias<<<16, 256, 0, stream>>>(b_ih, b_hh, W_hh, W_ih, b_h2h, bcombo, b0, bconst);
  k_fillx<<<2048, 256, 0, stream>>>(W_ih, Whf);
  k_len<<<1, 256, 0, stream>>>(lens, dout);

  k_main<<<256, 512, 0, stream>>>(x, Whf, Wcombo, b0, bconst, bcombo, h0, h1, gs, dout);
}